// Round 4
// baseline (10160.569 us; speedup 1.0000x reference)
//
#include <hip/hip_runtime.h>

#define BB 64
#define TT 64
#define DD 256
#define TAA 128
#define UU 256
#define VV 50257
#define NBLK 256
#define NV 208           // vocab span per block (13 x 16)
#define NVK 224          // padded K for fb GEMM (7 x 32)
#define W1ROWS 53248     // NBLK*NV, zero-padded rows >= VV
#define EMBCOLS 53248
#define NT 1024          // threads per block (16 waves): 4 waves/SIMD
// LDS layout (bytes)
#define OFF_W1   0                   // 208 rows x 264B  (stride 66 dwords)
#define OFF_EMB  54912               // 256 rows x 232B  (stride 58 dwords)
#define OFF_P    114304              // 64 rows x 232B
#define OFF_SA   129152              // 64 rows x 264B   (ca transients alias here)
// transients (alias sA): red4 16384 | fbL 1024 | rhL 1024 | cL 1024 | s1L 1024
//                        s2L 1024 | eL 512 | zredL 1024  => 23040 B
#define OFF_HL   152192              // 256 floats
#define OFF_ZP   153216              // 64 rows x 4 quarters partial-Z (1024B)
#define SMEM_BYTES 154240

typedef __attribute__((ext_vector_type(4))) float floatx4;
typedef unsigned long long ull_t;

__device__ __forceinline__ float bf2f(unsigned short u) {
  union { unsigned int i; float f; } c; c.i = ((unsigned int)u) << 16; return c.f;
}
__device__ __forceinline__ unsigned short f2bf(float f) {
  union { float f; unsigned int i; } c; c.f = f;
  return (unsigned short)((c.i + 0x7fffu + ((c.i >> 16) & 1u)) >> 16);
}
__device__ __forceinline__ float hsig(float x) {
  return fminf(1.0f, fmaxf(0.0f, 0.2f * x + 0.5f));
}
__device__ __forceinline__ unsigned int pk4_fp8(float a, float b, float c, float d) {
  unsigned int r = 0;
  r = __builtin_amdgcn_cvt_pk_fp8_f32(a, b, r, false);
  r = __builtin_amdgcn_cvt_pk_fp8_f32(c, d, r, true);
  return r;
}

// ---- coherent (cross-XCD) per-access ops; no cache-walk fences
__device__ __forceinline__ void st_f(float* p, float v) {
  __hip_atomic_store(p, v, __ATOMIC_RELAXED, __HIP_MEMORY_SCOPE_AGENT);
}
__device__ __forceinline__ float ld_f(const float* p) {
  return __hip_atomic_load(p, __ATOMIC_RELAXED, __HIP_MEMORY_SCOPE_AGENT);
}
__device__ __forceinline__ void st_u16(unsigned short* p, unsigned short v) {
  __hip_atomic_store(p, v, __ATOMIC_RELAXED, __HIP_MEMORY_SCOPE_AGENT);
}
__device__ __forceinline__ void st_u32(unsigned int* p, unsigned int v) {
  __hip_atomic_store(p, v, __ATOMIC_RELAXED, __HIP_MEMORY_SCOPE_AGENT);
}
__device__ __forceinline__ unsigned int ld_u32(const unsigned int* p) {
  return __hip_atomic_load(p, __ATOMIC_RELAXED, __HIP_MEMORY_SCOPE_AGENT);
}
__device__ __forceinline__ ull_t ld_u64(const ull_t* p) {
  return __hip_atomic_load(p, __ATOMIC_RELAXED, __HIP_MEMORY_SCOPE_AGENT);
}

// hierarchical barrier: 8 arrival lines (128B apart) + master line
__device__ __forceinline__ void gbar(ull_t* bar, int phase) {
  asm volatile("s_waitcnt vmcnt(0)" ::: "memory");
  __syncthreads();
  if (threadIdx.x == 0) {
    ull_t* myc = (ull_t*)((char*)bar + 128 * (1 + (blockIdx.x & 7)));
    ull_t t1 = __hip_atomic_fetch_add(myc, 1ull, __ATOMIC_RELAXED,
                                      __HIP_MEMORY_SCOPE_AGENT) + 1ull;
    if (t1 == (ull_t)(32 * phase)) {
      __hip_atomic_fetch_add(bar, 1ull, __ATOMIC_RELAXED, __HIP_MEMORY_SCOPE_AGENT);
    }
    while (__hip_atomic_load(bar, __ATOMIC_RELAXED, __HIP_MEMORY_SCOPE_AGENT) <
           (ull_t)(8 * phase))
      __builtin_amdgcn_s_sleep(4);
  }
  __syncthreads();
}

// ---------------- prep kernels ----------------

__global__ void k_f2bf(const float* __restrict__ in, unsigned short* __restrict__ out, int n) {
  int i = blockIdx.x * 256 + threadIdx.x;
  int stride = gridDim.x * 256;
  for (; i < n; i += stride) out[i] = f2bf(in[i]);
}

// W_o1 (256 x 50257) fp32 -> w1g (53248 x 256) fp8, zero-padded rows
__global__ void k_tw1(const float* __restrict__ w, unsigned int* __restrict__ o) {
  __shared__ float tile[32][33];  // [k_local][v_local]
  const int bx = blockIdx.x, by = blockIdx.y;
  const int tx = threadIdx.x, ty = threadIdx.y;
#pragma unroll
  for (int i = 0; i < 4; ++i) {
    int k = by * 32 + ty + i * 8;
    int v = bx * 32 + tx;
    tile[ty + i * 8][tx] = (v < VV) ? w[(size_t)k * VV + v] : 0.0f;
  }
  __syncthreads();
  const int t = ty * 32 + tx;      // 0..255
  const int vl = t >> 3;           // 0..31
  const int cg = t & 7;            // 0..7 (4 k each)
  unsigned int pk = pk4_fp8(tile[cg * 4 + 0][vl], tile[cg * 4 + 1][vl],
                            tile[cg * 4 + 2][vl], tile[cg * 4 + 3][vl]);
  o[(size_t)(bx * 32 + vl) * 64 + by * 8 + cg] = pk;
}

// embedding (50257 x 256) fp32 -> embg (256 x 53248) fp8, zero-padded cols
__global__ void k_temb(const float* __restrict__ e, unsigned int* __restrict__ o) {
  __shared__ float tile[32][33];  // [v_local][d_local]
  const int bx = blockIdx.x, by = blockIdx.y;
  const int tx = threadIdx.x, ty = threadIdx.y;
#pragma unroll
  for (int i = 0; i < 4; ++i) {
    int v = bx * 32 + ty + i * 8;
    int d = by * 32 + tx;
    tile[ty + i * 8][tx] = (v < VV) ? e[(size_t)v * 256 + d] : 0.0f;
  }
  __syncthreads();
  const int t = ty * 32 + tx;
  const int dl = t >> 3;           // 0..31
  const int vg = t & 7;            // 0..7 (4 v each)
  unsigned int pk = pk4_fp8(tile[vg * 4 + 0][dl], tile[vg * 4 + 1][dl],
                            tile[vg * 4 + 2][dl], tile[vg * 4 + 3][dl]);
  o[(size_t)(by * 32 + dl) * 13312 + bx * 8 + vg] = pk;
}

// xp = x(4096x256) @ kernel(256x768) + bias, fp32
__global__ void k_xp(const float* __restrict__ x, const float* __restrict__ kern,
                     const float* __restrict__ bias, float* __restrict__ xp) {
  __shared__ float xs[256][20];
  const int r0 = blockIdx.x * 16;
  const int tid = threadIdx.x;
  for (int idx = tid; idx < 16 * 256; idx += 256) {
    int rr = idx >> 8;
    int k = idx & 255;
    xs[k][rr] = x[(size_t)(r0 + rr) * 256 + k];
  }
  __syncthreads();
  float acc[16][3];
#pragma unroll
  for (int rr = 0; rr < 16; ++rr) {
    acc[rr][0] = bias[tid];
    acc[rr][1] = bias[256 + tid];
    acc[rr][2] = bias[512 + tid];
  }
  for (int k = 0; k < 256; ++k) {
    float k0 = kern[k * 768 + tid];
    float k1 = kern[k * 768 + 256 + tid];
    float k2 = kern[k * 768 + 512 + tid];
#pragma unroll
    for (int rr = 0; rr < 16; ++rr) {
      float xv = xs[k][rr];
      acc[rr][0] = fmaf(xv, k0, acc[rr][0]);
      acc[rr][1] = fmaf(xv, k1, acc[rr][1]);
      acc[rr][2] = fmaf(xv, k2, acc[rr][2]);
    }
  }
  for (int rr = 0; rr < 16; ++rr) {
    xp[(size_t)(r0 + rr) * 768 + tid] = acc[rr][0];
    xp[(size_t)(r0 + rr) * 768 + 256 + tid] = acc[rr][1];
    xp[(size_t)(r0 + rr) * 768 + 512 + tid] = acc[rr][2];
  }
}

// ---------------- main persistent kernel ----------------

// amdgpu_waves_per_eu(4,4): LDS (154KB, dynamic -> invisible to regalloc) caps
// us at 1 block/CU = 4 waves/EU. Without the max clamp the backend targets
// 8 waves/EU, squeezes to 64 VGPR and spills the MFMA frag arrays -> 4.3GB
// scratch HBM traffic (R2/R3 post-mortem). Clamp -> budget 128 VGPR, no spill.
__global__ void
__attribute__((amdgpu_flat_work_group_size(NT, NT), amdgpu_waves_per_eu(4, 4)))
gru_main(
    const float* __restrict__ att,            // (64,128,256) fp32
    const float* __restrict__ aab,            // after_att_bias (512) fp32
    const unsigned short* __restrict__ kbf,   // kernel bf16 (256x768)
    const unsigned short* __restrict__ rkbf,  // recurrent_kernel bf16 (256x768)
    const unsigned short* __restrict__ aabf,  // after_att_kernel bf16 (256x512)
    const float* __restrict__ xp,             // (4096x768) fp32
    const unsigned int* __restrict__ w1g,     // (53248 x 256) fp8 as u32
    const unsigned int* __restrict__ embg,    // (256 x 53248) fp8 as u32
    unsigned int* __restrict__ s8,            // (64 x 256) fp8 as u32 (64x64)
    unsigned short* __restrict__ pfb,         // [row 64][g 256][col 256] bf16
    float* __restrict__ psum,                 // [row 64][g 256] fp32
    ull_t* __restrict__ bar,
    float* __restrict__ y)                    // d_out (64,64,256) fp32
{
  extern __shared__ char smem[];
  char* w1p  = smem + OFF_W1;
  char* embp = smem + OFF_EMB;
  char* Pp   = smem + OFF_P;
  char* sAp  = smem + OFF_SA;
  float* red4  = (float*)(smem + OFF_SA);            // 16384B (16x256 partials)
  float* fbL   = (float*)(smem + OFF_SA + 16384);
  float* rhL   = (float*)(smem + OFF_SA + 17408);
  float* cL    = (float*)(smem + OFF_SA + 18432);
  float* s1L   = (float*)(smem + OFF_SA + 19456);
  float* s2L   = (float*)(smem + OFF_SA + 20480);
  float* eL    = (float*)(smem + OFF_SA + 21504);    // 512B
  float* zredL = (float*)(smem + OFF_SA + 22016);    // 1024B
  float* hL    = (float*)(smem + OFF_HL);
  float* zpartL= (float*)(smem + OFF_ZP);            // 64 rows x 4 quarters

  const int blk = blockIdx.x;
  const int tid = threadIdx.x;
  const int b = blk;           // batch index when blk < 64
  const int vbase = blk * NV;

  const int w = tid >> 6;      // 0..15
  const int lane = tid & 63;
  const int w2 = w & 3;        // MFMA row-group (batch rows 16*w2..16*w2+15)
  const int quarter = w >> 2;  // 0..3 (vocab/dt quarter)
  const int lq = lane >> 4;
  const int li = lane & 15;

  // ---- prologue: weights -> LDS (once)
  {
    unsigned int* dst = (unsigned int*)w1p;
    for (int i = tid; i < NV * 64; i += NT) {
      int r = i >> 6, c = i & 63;
      dst[r * 66 + c] = w1g[(size_t)(vbase + r) * 64 + c];
    }
    unsigned int* ed = (unsigned int*)embp;
    for (int i = tid; i < 256 * 52; i += NT) {
      int r = i / 52, c = i - r * 52;
      ed[r * 58 + c] = embg[(size_t)r * 13312 + blk * 52 + c];
    }
    for (int i = tid; i < 256 * 6; i += NT) {  // zero emb K-pad cols
      int r = i / 6, c = i - r * 6;
      ed[r * 58 + 52 + c] = 0u;
    }
    unsigned int* Pd = (unsigned int*)Pp;
    for (int i = tid; i < 64 * 6; i += NT) {   // zero P K-pad cols
      int r = i / 6, c = i - r * 6;
      Pd[r * 58 + 52 + c] = 0u;
    }
  }

  auto attention = [&]() {
    // e logits: 128 rows x 8 threads/row (32-dim partials, shfl combine)
    {
      const int r = tid >> 3, q = tid & 7;
      const float* ar = att + (size_t)(b * TAA + r) * DD + q * 32;
      const float* hp = hL + q * 32;
      float l0 = 0.f, l1 = 0.f;
#pragma unroll
      for (int dd = 0; dd < 32; dd += 8) {
        float4 a0 = *reinterpret_cast<const float4*>(ar + dd);
        float4 a1 = *reinterpret_cast<const float4*>(ar + dd + 4);
        l0 += a0.x * hp[dd] + a0.y * hp[dd + 1] + a0.z * hp[dd + 2] + a0.w * hp[dd + 3];
        l1 += a1.x * hp[dd + 4] + a1.y * hp[dd + 5] + a1.z * hp[dd + 6] + a1.w * hp[dd + 7];
      }
      float s = l0 + l1;
      s += __shfl_xor(s, 1);
      s += __shfl_xor(s, 2);
      s += __shfl_xor(s, 4);
      if (q == 0) eL[r] = s;
    }
    __syncthreads();
    if (tid < 64) {
      float l0 = eL[tid], l1 = eL[tid + 64];
      float m = fmaxf(l0, l1);
#pragma unroll
      for (int off = 32; off > 0; off >>= 1) m = fmaxf(m, __shfl_xor(m, off));
      float e0 = __expf(l0 - m), e1 = __expf(l1 - m);
      float s = e0 + e1;
#pragma unroll
      for (int off = 32; off > 0; off >>= 1) s += __shfl_xor(s, off);
      float inv = 1.0f / s;
      eL[tid] = e0 * inv;
      eL[tid + 64] = e1 * inv;
    }
    __syncthreads();
    // c = e @ att : 256 outs x 4 threads/out (32-ta partials)
    {
      const int d = tid & 255, g = tid >> 8;
      const float* ab = att + (size_t)b * TAA * DD + d;
      float c0 = 0.f, c1 = 0.f;
#pragma unroll 4
      for (int ta = g * 32; ta < g * 32 + 32; ta += 2) {
        c0 += eL[ta] * ab[(size_t)ta * DD];
        c1 += eL[ta + 1] * ab[(size_t)(ta + 1) * DD];
      }
      red4[tid] = c0 + c1;
    }
    __syncthreads();
    if (tid < 256)
      cL[tid] = red4[tid] + red4[tid + 256] + red4[tid + 512] + red4[tid + 768];
    __syncthreads();
    // s1: 256 outs x 4 threads/out (64-k partials)
    {
      const int out = tid & 255, g = tid >> 8;
      float a0 = g ? 0.f : aab[out], a1 = 0.f;
      for (int k = g * 64; k < g * 64 + 64; k += 2) {
        a0 += cL[k] * bf2f(aabf[k * 512 + out]);
        a1 += cL[k + 1] * bf2f(aabf[(k + 1) * 512 + out]);
      }
      red4[tid] = a0 + a1;
    }
    __syncthreads();
    if (tid < 256)
      s1L[tid] = tanhf(red4[tid] + red4[tid + 256] + red4[tid + 512] + red4[tid + 768]);
    __syncthreads();
    // s2
    {
      const int out = tid & 255, g = tid >> 8;
      float a0 = g ? 0.f : aab[256 + out], a1 = 0.f;
      for (int k = g * 64; k < g * 64 + 64; k += 2) {
        a0 += s1L[k] * bf2f(aabf[k * 512 + 256 + out]);
        a1 += s1L[k + 1] * bf2f(aabf[(k + 1) * 512 + 256 + out]);
      }
      red4[tid] = a0 + a1;
    }
    __syncthreads();
    if (tid < 256)
      s2L[tid] = tanhf(red4[tid] + red4[tid + 256] + red4[tid + 512] + red4[tid + 768]);
    __syncthreads();
    if (tid < 64) {
      unsigned int pk = pk4_fp8(s2L[4 * tid], s2L[4 * tid + 1],
                                s2L[4 * tid + 2], s2L[4 * tid + 3]);
      st_u32(s8 + b * 64 + tid, pk);
    }
  };

  auto ca_step = [&](int t) {
    // fb partial reduction: 16 waves x 16 g each
    {
      const int g16 = tid >> 6;
      const int dq = tid & 63;
      float a0 = 0, a1 = 0, a2 = 0, a3 = 0;
      const ull_t* base = (const ull_t*)pfb + (size_t)b * (256 * 64) + dq;
      for (int g = g16; g < NBLK; g += 16) {
        ull_t u = ld_u64(base + g * 64);
        a0 += __uint_as_float((unsigned)(u << 16));
        a1 += __uint_as_float((unsigned)u & 0xffff0000u);
        a2 += __uint_as_float(((unsigned)(u >> 16)) & 0xffff0000u);
        a3 += __uint_as_float(((unsigned)(u >> 32)) & 0xffff0000u);
      }
      *reinterpret_cast<float4*>(red4 + g16 * 256 + dq * 4) =
          make_float4(a0, a1, a2, a3);
      if (tid < 256) zredL[tid] = ld_f(psum + b * 256 + tid);
    }
    __syncthreads();
    if (tid < 64) {
      float z2 = zredL[tid] + zredL[tid + 64] + zredL[tid + 128] + zredL[tid + 192];
#pragma unroll
      for (int off = 32; off > 0; off >>= 1) z2 += __shfl_xor(z2, off);
      if (tid == 0) zredL[0] = z2;
    }
    __syncthreads();
    if (tid < 256) {
      float invZ = 1.0f / zredL[0];
      float s = 0.f;
#pragma unroll
      for (int j = 0; j < 16; ++j) s += red4[tid + j * 256];
      fbL[tid] = s * invZ;
    }
    __syncthreads();
    const float* xprow = xp + (size_t)(b * 64 + t) * 768;
    const int out = tid & 255, g = tid >> 8;
    // z,r gates: 4 threads/out, 64-k partials each
    {
      float z0 = g ? 0.f : xprow[out], z1 = 0.f;
      float r0 = g ? 0.f : xprow[256 + out], r1 = 0.f;
      for (int k = g * 64; k < g * 64 + 64; k += 2) {
        float fb0 = fbL[k], h0 = hL[k], fb1 = fbL[k + 1], h1 = hL[k + 1];
        const unsigned short* kp0 = kbf + k * 768 + out;
        const unsigned short* up0 = rkbf + k * 768 + out;
        z0 += fb0 * bf2f(kp0[0]) + h0 * bf2f(up0[0]);
        r0 += fb0 * bf2f(kp0[256]) + h0 * bf2f(up0[256]);
        z1 += fb1 * bf2f(kp0[768]) + h1 * bf2f(up0[768]);
        r1 += fb1 * bf2f(kp0[1024]) + h1 * bf2f(up0[1024]);
      }
      red4[tid] = z0 + z1;
      red4[1024 + tid] = r0 + r1;
    }
    __syncthreads();
    float zf = 0.f;
    if (tid < 256) {
      zf = red4[tid] + red4[tid + 256] + red4[tid + 512] + red4[tid + 768];
      float rf = red4[1024 + tid] + red4[1280 + tid] + red4[1536 + tid] + red4[1792 + tid];
      rhL[tid] = hsig(rf) * hL[tid];
    }
    __syncthreads();
    // candidate: 4 threads/out, 64-k partials
    {
      float hp0 = g ? 0.f : xprow[512 + out], hp1 = 0.f;
      for (int k = g * 64; k < g * 64 + 64; k += 2) {
        hp0 += fbL[k] * bf2f(kbf[k * 768 + 512 + out]) +
               rhL[k] * bf2f(rkbf[k * 768 + 512 + out]);
        hp1 += fbL[k + 1] * bf2f(kbf[(k + 1) * 768 + 512 + out]) +
               rhL[k + 1] * bf2f(rkbf[(k + 1) * 768 + 512 + out]);
      }
      red4[2048 + tid] = hp0 + hp1;
    }
    __syncthreads();
    if (tid < 256) {
      float hh = tanhf(red4[2048 + tid] + red4[2304 + tid] +
                       red4[2560 + tid] + red4[2816 + tid]);
      float z = hsig(zf);
      float hn = z * hL[tid] + (1.0f - z) * hh;
      y[(size_t)(b * 64 + t) * 256 + tid] = hn;
      hL[tid] = hn;   // own element: no cross-thread read between write and here
    }
    __syncthreads();
  };

  auto b_phase = [&]() {
    // cooperative sA load: s8 (64x64 u32) -> sA LDS (stride 66 dwords)
    {
      unsigned int* sd = (unsigned int*)sAp;
      for (int i = tid; i < 4096; i += NT) {
        int r = i >> 6, c = i & 63;
        sd[r * 66 + c] = ld_u32(s8 + i);
      }
    }
    __syncthreads();
    // A-frags (s): all quarters use row-group w2
    long afr[8];
#pragma unroll
    for (int kk = 0; kk < 8; ++kk)
      afr[kk] = *reinterpret_cast<const long*>(sAp + (16 * w2 + li) * 264 + kk * 32 + lq * 8);
    float sacc[4] = {0.f, 0.f, 0.f, 0.f};
    // logits + exp + P(fp8): vocab tiles split across quarters (4/3/3/3)
    const int vt0 = (quarter == 0) ? 0 : 1 + 3 * quarter;
    const int vt1 = (quarter == 0) ? 4 : vt0 + 3;
    for (int vt = vt0; vt < vt1; ++vt) {
      floatx4 lacc = (floatx4){0.f, 0.f, 0.f, 0.f};
#pragma unroll
      for (int kk = 0; kk < 8; ++kk) {
        long bfr = *reinterpret_cast<const long*>(w1p + (vt * 16 + li) * 264 + kk * 32 + lq * 8);
        lacc = __builtin_amdgcn_mfma_f32_16x16x32_fp8_fp8(afr[kk], bfr, lacc, 0, 0, 0);
      }
      const int v = vbase + vt * 16 + li;
      const bool ok = (v < VV);
#pragma unroll
      for (int q = 0; q < 4; ++q) {
        float p = ok ? __expf(lacc[q]) : 0.0f;
        sacc[q] += p;
        unsigned int pb = __builtin_amdgcn_cvt_pk_fp8_f32(p, 0.f, 0u, false);
        Pp[(16 * w2 + lq * 4 + q) * 232 + vt * 16 + li] = (char)(pb & 0xff);
      }
    }
    // partial Z per quarter -> LDS; combined after barrier
#pragma unroll
    for (int q = 0; q < 4; ++q) {
      float s = sacc[q];
      s += __shfl_xor(s, 1);
      s += __shfl_xor(s, 2);
      s += __shfl_xor(s, 4);
      s += __shfl_xor(s, 8);
      if (li == 0) zpartL[(16 * w2 + lq * 4 + q) * 4 + quarter] = s;
    }
    __syncthreads();   // P complete (cross-quarter) + zpart complete
    if (tid < 64)
      st_f(psum + tid * 256 + blk,
           zpartL[4 * tid] + zpartL[4 * tid + 1] + zpartL[4 * tid + 2] + zpartL[4 * tid + 3]);
    // fb partial: P(fp8) @ emb(fp8), K = 224; dt tiles split across quarters
    long pfr[7];
#pragma unroll
    for (int kk = 0; kk < 7; ++kk)
      pfr[kk] = *reinterpret_cast<const long*>(Pp + (16 * w2 + li) * 232 + kk * 32 + lq * 8);
    const int dt0 = quarter * 4;
#pragma unroll 4
    for (int dt = dt0; dt < dt0 + 4; ++dt) {
      floatx4 f = (floatx4){0.f, 0.f, 0.f, 0.f};
#pragma unroll
      for (int kk = 0; kk < 7; ++kk) {
        long efr = *reinterpret_cast<const long*>(embp + (dt * 16 + li) * 232 + kk * 32 + lq * 8);
        f = __builtin_amdgcn_mfma_f32_16x16x32_fp8_fp8(pfr[kk], efr, f, 0, 0, 0);
      }
#pragma unroll
      for (int q = 0; q < 4; ++q) {
        int row = 16 * w2 + lq * 4 + q;
        st_u16(pfb + ((size_t)(row * 256 + blk)) * 256 + dt * 16 + li, f2bf(f[q]));
      }
    }
  };

  // ---- t = 0 pre-phase
  __syncthreads();
  if (blk < BB) {
    if (tid < 256) hL[tid] = 0.0f;
    __syncthreads();
    attention();
  }
  gbar(bar, 1);
  for (int t = 0; t < TT; ++t) {
    b_phase();
    gbar(bar, 2 + 2 * t);
    if (blk < BB) {
      ca_step(t);
      attention();
    }
    gbar(bar, 3 + 2 * t);
  }
}

// ---------------- host ----------------

extern "C" void kernel_launch(void* const* d_in, const int* in_sizes, int n_in,
                              void* d_out, int out_size, void* d_ws, size_t ws_size,
                              hipStream_t stream) {
  const float* x    = (const float*)d_in[0];
  const float* att  = (const float*)d_in[1];
  const float* kern = (const float*)d_in[2];
  const float* rk   = (const float*)d_in[3];
  const float* bias = (const float*)d_in[4];
  const float* aak  = (const float*)d_in[5];
  const float* aab  = (const float*)d_in[6];
  const float* w1   = (const float*)d_in[7];
  const float* emb  = (const float*)d_in[8];
  float* y = (float*)d_out;

  char* ws = (char*)d_ws;
  size_t o = 0;
  auto alloc = [&](size_t bytes) {
    char* p = ws + o;
    o += (bytes + 255) & ~(size_t)255;
    return p;
  };
  ull_t* bar = (ull_t*)alloc(2048);
  unsigned int* w1g  = (unsigned int*)alloc((size_t)W1ROWS * 256);       // fp8
  unsigned int* embg = (unsigned int*)alloc((size_t)256 * EMBCOLS);      // fp8
  unsigned short* kbf  = (unsigned short*)alloc((size_t)196608 * 2);
  unsigned short* rkbf = (unsigned short*)alloc((size_t)196608 * 2);
  unsigned short* aabf = (unsigned short*)alloc((size_t)131072 * 2);
  float* xp  = (float*)alloc((size_t)4096 * 768 * 4);
  unsigned int* s8 = (unsigned int*)alloc((size_t)64 * 64 * 4);
  unsigned short* pfb = (unsigned short*)alloc((size_t)64 * 256 * 256 * 2);
  float* psum = (float*)alloc((size_t)64 * 256 * 4);
  (void)ws_size; (void)in_sizes; (void)n_in; (void)out_size;

  static bool attr_done = false;
  if (!attr_done) {
    hipFuncSetAttribute((const void*)gru_main,
                        hipFuncAttributeMaxDynamicSharedMemorySize, SMEM_BYTES);
    attr_done = true;
  }

  hipMemsetAsync(bar, 0, 2048, stream);
  hipLaunchKernelGGL(k_f2bf, dim3(768), dim3(256), 0, stream, kern, kbf, 196608);
  hipLaunchKernelGGL(k_f2bf, dim3(768), dim3(256), 0, stream, rk, rkbf, 196608);
  hipLaunchKernelGGL(k_f2bf, dim3(512), dim3(256), 0, stream, aak, aabf, 131072);
  hipLaunchKernelGGL(k_tw1, dim3(1664, 8), dim3(32, 8), 0, stream, w1, w1g);
  hipLaunchKernelGGL(k_temb, dim3(1664, 8), dim3(32, 8), 0, stream, emb, embg);
  hipLaunchKernelGGL(k_xp, dim3(256), dim3(256), 0, stream, x, kern, bias, xp);
  hipLaunchKernelGGL(gru_main, dim3(NBLK), dim3(NT), SMEM_BYTES, stream,
                     att, aab, kbf, rkbf, aabf, xp, w1g, embg, s8, pfb, psum, bar, y);
}

// Round 5
// 10109.312 us; speedup vs baseline: 1.0051x; 1.0051x over previous
//
#include <hip/hip_runtime.h>

#define BB 64
#define TT 64
#define DD 256
#define TAA 128
#define UU 256
#define VV 50257
#define NBLK 256
#define NV 208           // vocab span per block (13 x 16)
#define NVK 224          // padded K for fb GEMM (7 x 32)
#define W1ROWS 53248     // NBLK*NV, zero-padded rows >= VV
#define EMBCOLS 53248
#define NT 1024          // threads per block (16 waves): 4 waves/SIMD
// LDS layout (bytes)
#define OFF_W1   0                   // 208 rows x 264B  (stride 66 dwords)
#define OFF_EMB  54912               // 256 rows x 232B  (stride 58 dwords)
#define OFF_P    114304              // 64 rows x 232B
#define OFF_SA   129152              // 64 rows x 264B   (ca transients alias here)
// transients (alias sA): red4 16384 | fbL 1024 | rhL 1024 | cL 1024 | s1L 1024
//                        s2L 1024 | eL 512 | zredL 1024  => 23040 B
#define OFF_HL   152192              // 256 floats
#define OFF_ZP   153216              // 64 rows x 4 quarters partial-Z (1024B)
#define SMEM_BYTES 154240

typedef __attribute__((ext_vector_type(4))) float floatx4;
typedef unsigned long long ull_t;

__device__ __forceinline__ float bf2f(unsigned short u) {
  union { unsigned int i; float f; } c; c.i = ((unsigned int)u) << 16; return c.f;
}
__device__ __forceinline__ unsigned short f2bf(float f) {
  union { float f; unsigned int i; } c; c.f = f;
  return (unsigned short)((c.i + 0x7fffu + ((c.i >> 16) & 1u)) >> 16);
}
__device__ __forceinline__ float hsig(float x) {
  return fminf(1.0f, fmaxf(0.0f, 0.2f * x + 0.5f));
}
__device__ __forceinline__ unsigned int pk4_fp8(float a, float b, float c, float d) {
  unsigned int r = 0;
  r = __builtin_amdgcn_cvt_pk_fp8_f32(a, b, r, false);
  r = __builtin_amdgcn_cvt_pk_fp8_f32(c, d, r, true);
  return r;
}

// ---- coherent (cross-XCD) per-access ops; no cache-walk fences
__device__ __forceinline__ void st_f(float* p, float v) {
  __hip_atomic_store(p, v, __ATOMIC_RELAXED, __HIP_MEMORY_SCOPE_AGENT);
}
__device__ __forceinline__ float ld_f(const float* p) {
  return __hip_atomic_load(p, __ATOMIC_RELAXED, __HIP_MEMORY_SCOPE_AGENT);
}
__device__ __forceinline__ void st_u16(unsigned short* p, unsigned short v) {
  __hip_atomic_store(p, v, __ATOMIC_RELAXED, __HIP_MEMORY_SCOPE_AGENT);
}
__device__ __forceinline__ void st_u32(unsigned int* p, unsigned int v) {
  __hip_atomic_store(p, v, __ATOMIC_RELAXED, __HIP_MEMORY_SCOPE_AGENT);
}
__device__ __forceinline__ unsigned int ld_u32(const unsigned int* p) {
  return __hip_atomic_load(p, __ATOMIC_RELAXED, __HIP_MEMORY_SCOPE_AGENT);
}
__device__ __forceinline__ ull_t ld_u64(const ull_t* p) {
  return __hip_atomic_load(p, __ATOMIC_RELAXED, __HIP_MEMORY_SCOPE_AGENT);
}

// hierarchical barrier: 8 arrival lines (128B apart) + master line
__device__ __forceinline__ void gbar(ull_t* bar, int phase) {
  asm volatile("s_waitcnt vmcnt(0)" ::: "memory");
  __syncthreads();
  if (threadIdx.x == 0) {
    ull_t* myc = (ull_t*)((char*)bar + 128 * (1 + (blockIdx.x & 7)));
    ull_t t1 = __hip_atomic_fetch_add(myc, 1ull, __ATOMIC_RELAXED,
                                      __HIP_MEMORY_SCOPE_AGENT) + 1ull;
    if (t1 == (ull_t)(32 * phase)) {
      __hip_atomic_fetch_add(bar, 1ull, __ATOMIC_RELAXED, __HIP_MEMORY_SCOPE_AGENT);
    }
    while (__hip_atomic_load(bar, __ATOMIC_RELAXED, __HIP_MEMORY_SCOPE_AGENT) <
           (ull_t)(8 * phase))
      __builtin_amdgcn_s_sleep(4);
  }
  __syncthreads();
}

// ---------------- prep kernels ----------------

__global__ void k_f2bf(const float* __restrict__ in, unsigned short* __restrict__ out, int n) {
  int i = blockIdx.x * 256 + threadIdx.x;
  int stride = gridDim.x * 256;
  for (; i < n; i += stride) out[i] = f2bf(in[i]);
}

// W_o1 (256 x 50257) fp32 -> w1g (53248 x 256) fp8, zero-padded rows
__global__ void k_tw1(const float* __restrict__ w, unsigned int* __restrict__ o) {
  __shared__ float tile[32][33];  // [k_local][v_local]
  const int bx = blockIdx.x, by = blockIdx.y;
  const int tx = threadIdx.x, ty = threadIdx.y;
#pragma unroll
  for (int i = 0; i < 4; ++i) {
    int k = by * 32 + ty + i * 8;
    int v = bx * 32 + tx;
    tile[ty + i * 8][tx] = (v < VV) ? w[(size_t)k * VV + v] : 0.0f;
  }
  __syncthreads();
  const int t = ty * 32 + tx;      // 0..255
  const int vl = t >> 3;           // 0..31
  const int cg = t & 7;            // 0..7 (4 k each)
  unsigned int pk = pk4_fp8(tile[cg * 4 + 0][vl], tile[cg * 4 + 1][vl],
                            tile[cg * 4 + 2][vl], tile[cg * 4 + 3][vl]);
  o[(size_t)(bx * 32 + vl) * 64 + by * 8 + cg] = pk;
}

// embedding (50257 x 256) fp32 -> embg (256 x 53248) fp8, zero-padded cols
__global__ void k_temb(const float* __restrict__ e, unsigned int* __restrict__ o) {
  __shared__ float tile[32][33];  // [v_local][d_local]
  const int bx = blockIdx.x, by = blockIdx.y;
  const int tx = threadIdx.x, ty = threadIdx.y;
#pragma unroll
  for (int i = 0; i < 4; ++i) {
    int v = bx * 32 + ty + i * 8;
    int d = by * 32 + tx;
    tile[ty + i * 8][tx] = (v < VV) ? e[(size_t)v * 256 + d] : 0.0f;
  }
  __syncthreads();
  const int t = ty * 32 + tx;
  const int dl = t >> 3;           // 0..31
  const int vg = t & 7;            // 0..7 (4 v each)
  unsigned int pk = pk4_fp8(tile[vg * 4 + 0][dl], tile[vg * 4 + 1][dl],
                            tile[vg * 4 + 2][dl], tile[vg * 4 + 3][dl]);
  o[(size_t)(by * 32 + dl) * 13312 + bx * 8 + vg] = pk;
}

// xp = x(4096x256) @ kernel(256x768) + bias, fp32
__global__ void k_xp(const float* __restrict__ x, const float* __restrict__ kern,
                     const float* __restrict__ bias, float* __restrict__ xp) {
  __shared__ float xs[256][20];
  const int r0 = blockIdx.x * 16;
  const int tid = threadIdx.x;
  for (int idx = tid; idx < 16 * 256; idx += 256) {
    int rr = idx >> 8;
    int k = idx & 255;
    xs[k][rr] = x[(size_t)(r0 + rr) * 256 + k];
  }
  __syncthreads();
  float acc[16][3];
#pragma unroll
  for (int rr = 0; rr < 16; ++rr) {
    acc[rr][0] = bias[tid];
    acc[rr][1] = bias[256 + tid];
    acc[rr][2] = bias[512 + tid];
  }
  for (int k = 0; k < 256; ++k) {
    float k0 = kern[k * 768 + tid];
    float k1 = kern[k * 768 + 256 + tid];
    float k2 = kern[k * 768 + 512 + tid];
#pragma unroll
    for (int rr = 0; rr < 16; ++rr) {
      float xv = xs[k][rr];
      acc[rr][0] = fmaf(xv, k0, acc[rr][0]);
      acc[rr][1] = fmaf(xv, k1, acc[rr][1]);
      acc[rr][2] = fmaf(xv, k2, acc[rr][2]);
    }
  }
  for (int rr = 0; rr < 16; ++rr) {
    xp[(size_t)(r0 + rr) * 768 + tid] = acc[rr][0];
    xp[(size_t)(r0 + rr) * 768 + 256 + tid] = acc[rr][1];
    xp[(size_t)(r0 + rr) * 768 + 512 + tid] = acc[rr][2];
  }
}

// ---------------- main persistent kernel ----------------

// The backend pins this kernel to a 64 arch-VGPR budget (gfx950 unified
// VGPR/AGPR file splits the 128-reg 4-wave/EU budget when MFMA is present;
// R2-R4 post-mortems). So b_phase is written register-light: MFMA fragments
// stream from LDS per-instruction, never held in register arrays.
__global__ void
__attribute__((amdgpu_flat_work_group_size(NT, NT), amdgpu_waves_per_eu(4, 4)))
gru_main(
    const float* __restrict__ att,            // (64,128,256) fp32
    const float* __restrict__ aab,            // after_att_bias (512) fp32
    const unsigned short* __restrict__ kbf,   // kernel bf16 (256x768)
    const unsigned short* __restrict__ rkbf,  // recurrent_kernel bf16 (256x768)
    const unsigned short* __restrict__ aabf,  // after_att_kernel bf16 (256x512)
    const float* __restrict__ xp,             // (4096x768) fp32
    const unsigned int* __restrict__ w1g,     // (53248 x 256) fp8 as u32
    const unsigned int* __restrict__ embg,    // (256 x 53248) fp8 as u32
    unsigned int* __restrict__ s8,            // (64 x 256) fp8 as u32 (64x64)
    unsigned short* __restrict__ pfb,         // [row 64][g 256][col 256] bf16
    float* __restrict__ psum,                 // [row 64][g 256] fp32
    ull_t* __restrict__ bar,
    float* __restrict__ y)                    // d_out (64,64,256) fp32
{
  extern __shared__ char smem[];
  char* w1p  = smem + OFF_W1;
  char* embp = smem + OFF_EMB;
  char* Pp   = smem + OFF_P;
  char* sAp  = smem + OFF_SA;
  float* red4  = (float*)(smem + OFF_SA);            // 16384B (16x256 partials)
  float* fbL   = (float*)(smem + OFF_SA + 16384);
  float* rhL   = (float*)(smem + OFF_SA + 17408);
  float* cL    = (float*)(smem + OFF_SA + 18432);
  float* s1L   = (float*)(smem + OFF_SA + 19456);
  float* s2L   = (float*)(smem + OFF_SA + 20480);
  float* eL    = (float*)(smem + OFF_SA + 21504);    // 512B
  float* zredL = (float*)(smem + OFF_SA + 22016);    // 1024B
  float* hL    = (float*)(smem + OFF_HL);
  float* zpartL= (float*)(smem + OFF_ZP);            // 64 rows x 4 quarters

  const int blk = blockIdx.x;
  const int tid = threadIdx.x;
  const int b = blk;           // batch index when blk < 64
  const int vbase = blk * NV;

  const int w = tid >> 6;      // 0..15
  const int lane = tid & 63;
  const int w2 = w & 3;        // MFMA row-group (batch rows 16*w2..16*w2+15)
  const int quarter = w >> 2;  // 0..3 (vocab/dt quarter)
  const int lq = lane >> 4;
  const int li = lane & 15;

  // ---- prologue: weights -> LDS (once)
  {
    unsigned int* dst = (unsigned int*)w1p;
    for (int i = tid; i < NV * 64; i += NT) {
      int r = i >> 6, c = i & 63;
      dst[r * 66 + c] = w1g[(size_t)(vbase + r) * 64 + c];
    }
    unsigned int* ed = (unsigned int*)embp;
    for (int i = tid; i < 256 * 52; i += NT) {
      int r = i / 52, c = i - r * 52;
      ed[r * 58 + c] = embg[(size_t)r * 13312 + blk * 52 + c];
    }
    for (int i = tid; i < 256 * 6; i += NT) {  // zero emb K-pad cols
      int r = i / 6, c = i - r * 6;
      ed[r * 58 + 52 + c] = 0u;
    }
    unsigned int* Pd = (unsigned int*)Pp;
    for (int i = tid; i < 64 * 6; i += NT) {   // zero P K-pad cols
      int r = i / 6, c = i - r * 6;
      Pd[r * 58 + 52 + c] = 0u;
    }
  }

  auto attention = [&]() {
    // e logits: 128 rows x 8 threads/row (32-dim partials, shfl combine)
    {
      const int r = tid >> 3, q = tid & 7;
      const float* ar = att + (size_t)(b * TAA + r) * DD + q * 32;
      const float* hp = hL + q * 32;
      float l0 = 0.f, l1 = 0.f;
#pragma unroll
      for (int dd = 0; dd < 32; dd += 8) {
        float4 a0 = *reinterpret_cast<const float4*>(ar + dd);
        float4 a1 = *reinterpret_cast<const float4*>(ar + dd + 4);
        l0 += a0.x * hp[dd] + a0.y * hp[dd + 1] + a0.z * hp[dd + 2] + a0.w * hp[dd + 3];
        l1 += a1.x * hp[dd + 4] + a1.y * hp[dd + 5] + a1.z * hp[dd + 6] + a1.w * hp[dd + 7];
      }
      float s = l0 + l1;
      s += __shfl_xor(s, 1);
      s += __shfl_xor(s, 2);
      s += __shfl_xor(s, 4);
      if (q == 0) eL[r] = s;
    }
    __syncthreads();
    if (tid < 64) {
      float l0 = eL[tid], l1 = eL[tid + 64];
      float m = fmaxf(l0, l1);
#pragma unroll
      for (int off = 32; off > 0; off >>= 1) m = fmaxf(m, __shfl_xor(m, off));
      float e0 = __expf(l0 - m), e1 = __expf(l1 - m);
      float s = e0 + e1;
#pragma unroll
      for (int off = 32; off > 0; off >>= 1) s += __shfl_xor(s, off);
      float inv = 1.0f / s;
      eL[tid] = e0 * inv;
      eL[tid + 64] = e1 * inv;
    }
    __syncthreads();
    // c = e @ att : 256 outs x 4 threads/out (32-ta partials)
    {
      const int d = tid & 255, g = tid >> 8;
      const float* ab = att + (size_t)b * TAA * DD + d;
      float c0 = 0.f, c1 = 0.f;
#pragma unroll 4
      for (int ta = g * 32; ta < g * 32 + 32; ta += 2) {
        c0 += eL[ta] * ab[(size_t)ta * DD];
        c1 += eL[ta + 1] * ab[(size_t)(ta + 1) * DD];
      }
      red4[tid] = c0 + c1;
    }
    __syncthreads();
    if (tid < 256)
      cL[tid] = red4[tid] + red4[tid + 256] + red4[tid + 512] + red4[tid + 768];
    __syncthreads();
    // s1: 256 outs x 4 threads/out (64-k partials)
    {
      const int out = tid & 255, g = tid >> 8;
      float a0 = g ? 0.f : aab[out], a1 = 0.f;
      for (int k = g * 64; k < g * 64 + 64; k += 2) {
        a0 += cL[k] * bf2f(aabf[k * 512 + out]);
        a1 += cL[k + 1] * bf2f(aabf[(k + 1) * 512 + out]);
      }
      red4[tid] = a0 + a1;
    }
    __syncthreads();
    if (tid < 256)
      s1L[tid] = tanhf(red4[tid] + red4[tid + 256] + red4[tid + 512] + red4[tid + 768]);
    __syncthreads();
    // s2
    {
      const int out = tid & 255, g = tid >> 8;
      float a0 = g ? 0.f : aab[256 + out], a1 = 0.f;
      for (int k = g * 64; k < g * 64 + 64; k += 2) {
        a0 += s1L[k] * bf2f(aabf[k * 512 + 256 + out]);
        a1 += s1L[k + 1] * bf2f(aabf[(k + 1) * 512 + 256 + out]);
      }
      red4[tid] = a0 + a1;
    }
    __syncthreads();
    if (tid < 256)
      s2L[tid] = tanhf(red4[tid] + red4[tid + 256] + red4[tid + 512] + red4[tid + 768]);
    __syncthreads();
    if (tid < 64) {
      unsigned int pk = pk4_fp8(s2L[4 * tid], s2L[4 * tid + 1],
                                s2L[4 * tid + 2], s2L[4 * tid + 3]);
      st_u32(s8 + b * 64 + tid, pk);
    }
  };

  auto ca_step = [&](int t) {
    // fb partial reduction: 16 waves x 16 g each
    {
      const int g16 = tid >> 6;
      const int dq = tid & 63;
      float a0 = 0, a1 = 0, a2 = 0, a3 = 0;
      const ull_t* base = (const ull_t*)pfb + (size_t)b * (256 * 64) + dq;
      for (int g = g16; g < NBLK; g += 16) {
        ull_t u = ld_u64(base + g * 64);
        a0 += __uint_as_float((unsigned)(u << 16));
        a1 += __uint_as_float((unsigned)u & 0xffff0000u);
        a2 += __uint_as_float(((unsigned)(u >> 16)) & 0xffff0000u);
        a3 += __uint_as_float(((unsigned)(u >> 32)) & 0xffff0000u);
      }
      *reinterpret_cast<float4*>(red4 + g16 * 256 + dq * 4) =
          make_float4(a0, a1, a2, a3);
      if (tid < 256) zredL[tid] = ld_f(psum + b * 256 + tid);
    }
    __syncthreads();
    if (tid < 64) {
      float z2 = zredL[tid] + zredL[tid + 64] + zredL[tid + 128] + zredL[tid + 192];
#pragma unroll
      for (int off = 32; off > 0; off >>= 1) z2 += __shfl_xor(z2, off);
      if (tid == 0) zredL[0] = z2;
    }
    __syncthreads();
    if (tid < 256) {
      float invZ = 1.0f / zredL[0];
      float s = 0.f;
#pragma unroll
      for (int j = 0; j < 16; ++j) s += red4[tid + j * 256];
      fbL[tid] = s * invZ;
    }
    __syncthreads();
    const float* xprow = xp + (size_t)(b * 64 + t) * 768;
    const int out = tid & 255, g = tid >> 8;
    // z,r gates: 4 threads/out, 64-k partials each
    {
      float z0 = g ? 0.f : xprow[out], z1 = 0.f;
      float r0 = g ? 0.f : xprow[256 + out], r1 = 0.f;
      for (int k = g * 64; k < g * 64 + 64; k += 2) {
        float fb0 = fbL[k], h0 = hL[k], fb1 = fbL[k + 1], h1 = hL[k + 1];
        const unsigned short* kp0 = kbf + k * 768 + out;
        const unsigned short* up0 = rkbf + k * 768 + out;
        z0 += fb0 * bf2f(kp0[0]) + h0 * bf2f(up0[0]);
        r0 += fb0 * bf2f(kp0[256]) + h0 * bf2f(up0[256]);
        z1 += fb1 * bf2f(kp0[768]) + h1 * bf2f(up0[768]);
        r1 += fb1 * bf2f(kp0[1024]) + h1 * bf2f(up0[1024]);
      }
      red4[tid] = z0 + z1;
      red4[1024 + tid] = r0 + r1;
    }
    __syncthreads();
    float zf = 0.f;
    if (tid < 256) {
      zf = red4[tid] + red4[tid + 256] + red4[tid + 512] + red4[tid + 768];
      float rf = red4[1024 + tid] + red4[1280 + tid] + red4[1536 + tid] + red4[1792 + tid];
      rhL[tid] = hsig(rf) * hL[tid];
    }
    __syncthreads();
    // candidate: 4 threads/out, 64-k partials
    {
      float hp0 = g ? 0.f : xprow[512 + out], hp1 = 0.f;
      for (int k = g * 64; k < g * 64 + 64; k += 2) {
        hp0 += fbL[k] * bf2f(kbf[k * 768 + 512 + out]) +
               rhL[k] * bf2f(rkbf[k * 768 + 512 + out]);
        hp1 += fbL[k + 1] * bf2f(kbf[(k + 1) * 768 + 512 + out]) +
               rhL[k + 1] * bf2f(rkbf[(k + 1) * 768 + 512 + out]);
      }
      red4[2048 + tid] = hp0 + hp1;
    }
    __syncthreads();
    if (tid < 256) {
      float hh = tanhf(red4[2048 + tid] + red4[2304 + tid] +
                       red4[2560 + tid] + red4[2816 + tid]);
      float z = hsig(zf);
      float hn = z * hL[tid] + (1.0f - z) * hh;
      y[(size_t)(b * 64 + t) * 256 + tid] = hn;
      hL[tid] = hn;   // own element: no cross-thread read between write and here
    }
    __syncthreads();
  };

  auto b_phase = [&]() {
    // cooperative sA load: s8 (64x64 u32) -> sA LDS (stride 66 dwords)
    {
      unsigned int* sd = (unsigned int*)sAp;
      for (int i = tid; i < 4096; i += NT) {
        int r = i >> 6, c = i & 63;
        sd[r * 66 + c] = ld_u32(s8 + i);
      }
    }
    __syncthreads();
    // Register-light: fragments stream from LDS per-MFMA (no afr[]/pfr[]
    // arrays -> no spill at the 64 arch-VGPR budget).
    const char* arow = sAp + (16 * w2 + li) * 264 + lq * 8;
    float sacc[4] = {0.f, 0.f, 0.f, 0.f};
    // logits + exp + P(fp8): vocab tiles split across quarters (4/3/3/3)
    const int vt0 = (quarter == 0) ? 0 : 1 + 3 * quarter;
    const int vt1 = (quarter == 0) ? 4 : vt0 + 3;
#pragma unroll 1
    for (int vt = vt0; vt < vt1; ++vt) {
      const char* brow = w1p + (vt * 16 + li) * 264 + lq * 8;
      floatx4 lacc = (floatx4){0.f, 0.f, 0.f, 0.f};
#pragma unroll
      for (int kk = 0; kk < 8; ++kk) {
        long afr = *reinterpret_cast<const long*>(arow + kk * 32);
        long bfr = *reinterpret_cast<const long*>(brow + kk * 32);
        lacc = __builtin_amdgcn_mfma_f32_16x16x32_fp8_fp8(afr, bfr, lacc, 0, 0, 0);
      }
      const int v = vbase + vt * 16 + li;
      const bool ok = (v < VV);
#pragma unroll
      for (int q = 0; q < 4; ++q) {
        float p = ok ? __expf(lacc[q]) : 0.0f;
        sacc[q] += p;
        unsigned int pb = __builtin_amdgcn_cvt_pk_fp8_f32(p, 0.f, 0u, false);
        Pp[(16 * w2 + lq * 4 + q) * 232 + vt * 16 + li] = (char)(pb & 0xff);
      }
    }
    // partial Z per quarter -> LDS; combined after barrier
#pragma unroll
    for (int q = 0; q < 4; ++q) {
      float s = sacc[q];
      s += __shfl_xor(s, 1);
      s += __shfl_xor(s, 2);
      s += __shfl_xor(s, 4);
      s += __shfl_xor(s, 8);
      if (li == 0) zpartL[(16 * w2 + lq * 4 + q) * 4 + quarter] = s;
    }
    __syncthreads();   // P complete (cross-quarter) + zpart complete
    if (tid < 64)
      st_f(psum + tid * 256 + blk,
           zpartL[4 * tid] + zpartL[4 * tid + 1] + zpartL[4 * tid + 2] + zpartL[4 * tid + 3]);
    // fb partial: P(fp8) @ emb(fp8), K = 224; dt tiles split across quarters
    const char* prow = Pp + (16 * w2 + li) * 232 + lq * 8;
    const int dt0 = quarter * 4;
#pragma unroll 1
    for (int dt = dt0; dt < dt0 + 4; ++dt) {
      const char* erow = embp + (dt * 16 + li) * 232 + lq * 8;
      floatx4 f = (floatx4){0.f, 0.f, 0.f, 0.f};
#pragma unroll
      for (int kk = 0; kk < 7; ++kk) {
        long pfr = *reinterpret_cast<const long*>(prow + kk * 32);
        long efr = *reinterpret_cast<const long*>(erow + kk * 32);
        f = __builtin_amdgcn_mfma_f32_16x16x32_fp8_fp8(pfr, efr, f, 0, 0, 0);
      }
#pragma unroll
      for (int q = 0; q < 4; ++q) {
        int row = 16 * w2 + lq * 4 + q;
        st_u16(pfb + ((size_t)(row * 256 + blk)) * 256 + dt * 16 + li, f2bf(f[q]));
      }
    }
  };

  // ---- t = 0 pre-phase
  __syncthreads();
  if (blk < BB) {
    if (tid < 256) hL[tid] = 0.0f;
    __syncthreads();
    attention();
  }
  gbar(bar, 1);
  for (int t = 0; t < TT; ++t) {
    b_phase();
    gbar(bar, 2 + 2 * t);
    if (blk < BB) {
      ca_step(t);
      attention();
    }
    gbar(bar, 3 + 2 * t);
  }
}

// ---------------- host ----------------

extern "C" void kernel_launch(void* const* d_in, const int* in_sizes, int n_in,
                              void* d_out, int out_size, void* d_ws, size_t ws_size,
                              hipStream_t stream) {
  const float* x    = (const float*)d_in[0];
  const float* att  = (const float*)d_in[1];
  const float* kern = (const float*)d_in[2];
  const float* rk   = (const float*)d_in[3];
  const float* bias = (const float*)d_in[4];
  const float* aak  = (const float*)d_in[5];
  const float* aab  = (const float*)d_in[6];
  const float* w1   = (const float*)d_in[7];
  const float* emb  = (const float*)d_in[8];
  float* y = (float*)d_out;

  char* ws = (char*)d_ws;
  size_t o = 0;
  auto alloc = [&](size_t bytes) {
    char* p = ws + o;
    o += (bytes + 255) & ~(size_t)255;
    return p;
  };
  ull_t* bar = (ull_t*)alloc(2048);
  unsigned int* w1g  = (unsigned int*)alloc((size_t)W1ROWS * 256);       // fp8
  unsigned int* embg = (unsigned int*)alloc((size_t)256 * EMBCOLS);      // fp8
  unsigned short* kbf  = (unsigned short*)alloc((size_t)196608 * 2);
  unsigned short* rkbf = (unsigned short*)alloc((size_t)196608 * 2);
  unsigned short* aabf = (unsigned short*)alloc((size_t)131072 * 2);
  float* xp  = (float*)alloc((size_t)4096 * 768 * 4);
  unsigned int* s8 = (unsigned int*)alloc((size_t)64 * 64 * 4);
  unsigned short* pfb = (unsigned short*)alloc((size_t)64 * 256 * 256 * 2);
  float* psum = (float*)alloc((size_t)64 * 256 * 4);
  (void)ws_size; (void)in_sizes; (void)n_in; (void)out_size;

  static bool attr_done = false;
  if (!attr_done) {
    hipFuncSetAttribute((const void*)gru_main,
                        hipFuncAttributeMaxDynamicSharedMemorySize, SMEM_BYTES);
    attr_done = true;
  }

  hipMemsetAsync(bar, 0, 2048, stream);
  hipLaunchKernelGGL(k_f2bf, dim3(768), dim3(256), 0, stream, kern, kbf, 196608);
  hipLaunchKernelGGL(k_f2bf, dim3(768), dim3(256), 0, stream, rk, rkbf, 196608);
  hipLaunchKernelGGL(k_f2bf, dim3(512), dim3(256), 0, stream, aak, aabf, 131072);
  hipLaunchKernelGGL(k_tw1, dim3(1664, 8), dim3(32, 8), 0, stream, w1, w1g);
  hipLaunchKernelGGL(k_temb, dim3(1664, 8), dim3(32, 8), 0, stream, emb, embg);
  hipLaunchKernelGGL(k_xp, dim3(256), dim3(256), 0, stream, x, kern, bias, xp);
  hipLaunchKernelGGL(gru_main, dim3(NBLK), dim3(NT), SMEM_BYTES, stream,
                     att, aab, kbf, rkbf, aabf, xp, w1g, embg, s8, pfb, psum, bar, y);
}

// Round 6
// 3748.755 us; speedup vs baseline: 2.7104x; 2.6967x over previous
//
#include <hip/hip_runtime.h>

#define BB 64
#define TT 64
#define DD 256
#define TAA 128
#define UU 256
#define VV 50257
#define NBLK 256
#define NV 208           // vocab span per block (13 x 16)
#define NVK 224          // padded K for fb GEMM (7 x 32)
#define W1ROWS 53248     // NBLK*NV, zero-padded rows >= VV
#define EMBCOLS 53248
#define NT 512           // threads per block (8 waves): 2 waves/SIMD (R1-verified)
// LDS layout (bytes)
#define OFF_W1   0                   // 208 rows x 264B  (stride 66 dwords)
#define OFF_EMB  54912               // 256 rows x 232B  (stride 58 dwords)
#define OFF_P    114304              // 64 rows x 232B
#define OFF_SA   129152              // 64 rows x 264B = 16896B; red4 (16384B) aliases
#define OFF_TR   146048              // fbL 1024 | rhL 1024 | cL 1024 | s1L 1024
                                     // s2L 1024 | eL 512 | zredL 1024 => 6656B
#define OFF_HL   152704              // 256 floats
#define OFF_ZP   153728              // 64 rows x 2 halves partial-Z (512B)
#define SMEM_BYTES 154240

typedef __attribute__((ext_vector_type(4))) float floatx4;
typedef unsigned long long ull_t;

__device__ __forceinline__ float bf2f(unsigned short u) {
  union { unsigned int i; float f; } c; c.i = ((unsigned int)u) << 16; return c.f;
}
__device__ __forceinline__ unsigned short f2bf(float f) {
  union { float f; unsigned int i; } c; c.f = f;
  return (unsigned short)((c.i + 0x7fffu + ((c.i >> 16) & 1u)) >> 16);
}
__device__ __forceinline__ float hsig(float x) {
  return fminf(1.0f, fmaxf(0.0f, 0.2f * x + 0.5f));
}
__device__ __forceinline__ unsigned int pk4_fp8(float a, float b, float c, float d) {
  unsigned int r = 0;
  r = __builtin_amdgcn_cvt_pk_fp8_f32(a, b, r, false);
  r = __builtin_amdgcn_cvt_pk_fp8_f32(c, d, r, true);
  return r;
}

// ---- coherent (cross-XCD) per-access ops; no cache-walk fences
__device__ __forceinline__ void st_f(float* p, float v) {
  __hip_atomic_store(p, v, __ATOMIC_RELAXED, __HIP_MEMORY_SCOPE_AGENT);
}
__device__ __forceinline__ float ld_f(const float* p) {
  return __hip_atomic_load(p, __ATOMIC_RELAXED, __HIP_MEMORY_SCOPE_AGENT);
}
__device__ __forceinline__ void st_u16(unsigned short* p, unsigned short v) {
  __hip_atomic_store(p, v, __ATOMIC_RELAXED, __HIP_MEMORY_SCOPE_AGENT);
}
__device__ __forceinline__ void st_u32(unsigned int* p, unsigned int v) {
  __hip_atomic_store(p, v, __ATOMIC_RELAXED, __HIP_MEMORY_SCOPE_AGENT);
}
__device__ __forceinline__ unsigned int ld_u32(const unsigned int* p) {
  return __hip_atomic_load(p, __ATOMIC_RELAXED, __HIP_MEMORY_SCOPE_AGENT);
}
__device__ __forceinline__ ull_t ld_u64(const ull_t* p) {
  return __hip_atomic_load(p, __ATOMIC_RELAXED, __HIP_MEMORY_SCOPE_AGENT);
}

// hierarchical barrier: 8 arrival lines (128B apart) + master line
__device__ __forceinline__ void gbar(ull_t* bar, int phase) {
  asm volatile("s_waitcnt vmcnt(0)" ::: "memory");
  __syncthreads();
  if (threadIdx.x == 0) {
    ull_t* myc = (ull_t*)((char*)bar + 128 * (1 + (blockIdx.x & 7)));
    ull_t t1 = __hip_atomic_fetch_add(myc, 1ull, __ATOMIC_RELAXED,
                                      __HIP_MEMORY_SCOPE_AGENT) + 1ull;
    if (t1 == (ull_t)(32 * phase)) {
      __hip_atomic_fetch_add(bar, 1ull, __ATOMIC_RELAXED, __HIP_MEMORY_SCOPE_AGENT);
    }
    while (__hip_atomic_load(bar, __ATOMIC_RELAXED, __HIP_MEMORY_SCOPE_AGENT) <
           (ull_t)(8 * phase))
      __builtin_amdgcn_s_sleep(4);
  }
  __syncthreads();
}

// ---------------- prep kernels ----------------

__global__ void k_f2bf(const float* __restrict__ in, unsigned short* __restrict__ out, int n) {
  int i = blockIdx.x * 256 + threadIdx.x;
  int stride = gridDim.x * 256;
  for (; i < n; i += stride) out[i] = f2bf(in[i]);
}

// W_o1 (256 x 50257) fp32 -> w1g (53248 x 256) fp8, zero-padded rows
__global__ void k_tw1(const float* __restrict__ w, unsigned int* __restrict__ o) {
  __shared__ float tile[32][33];  // [k_local][v_local]
  const int bx = blockIdx.x, by = blockIdx.y;
  const int tx = threadIdx.x, ty = threadIdx.y;
#pragma unroll
  for (int i = 0; i < 4; ++i) {
    int k = by * 32 + ty + i * 8;
    int v = bx * 32 + tx;
    tile[ty + i * 8][tx] = (v < VV) ? w[(size_t)k * VV + v] : 0.0f;
  }
  __syncthreads();
  const int t = ty * 32 + tx;      // 0..255
  const int vl = t >> 3;           // 0..31
  const int cg = t & 7;            // 0..7 (4 k each)
  unsigned int pk = pk4_fp8(tile[cg * 4 + 0][vl], tile[cg * 4 + 1][vl],
                            tile[cg * 4 + 2][vl], tile[cg * 4 + 3][vl]);
  o[(size_t)(bx * 32 + vl) * 64 + by * 8 + cg] = pk;
}

// embedding (50257 x 256) fp32 -> embg (256 x 53248) fp8, zero-padded cols
__global__ void k_temb(const float* __restrict__ e, unsigned int* __restrict__ o) {
  __shared__ float tile[32][33];  // [v_local][d_local]
  const int bx = blockIdx.x, by = blockIdx.y;
  const int tx = threadIdx.x, ty = threadIdx.y;
#pragma unroll
  for (int i = 0; i < 4; ++i) {
    int v = bx * 32 + ty + i * 8;
    int d = by * 32 + tx;
    tile[ty + i * 8][tx] = (v < VV) ? e[(size_t)v * 256 + d] : 0.0f;
  }
  __syncthreads();
  const int t = ty * 32 + tx;
  const int dl = t >> 3;           // 0..31
  const int vg = t & 7;            // 0..7 (4 v each)
  unsigned int pk = pk4_fp8(tile[vg * 4 + 0][dl], tile[vg * 4 + 1][dl],
                            tile[vg * 4 + 2][dl], tile[vg * 4 + 3][dl]);
  o[(size_t)(by * 32 + dl) * 13312 + bx * 8 + vg] = pk;
}

// xp = x(4096x256) @ kernel(256x768) + bias, fp32
__global__ void k_xp(const float* __restrict__ x, const float* __restrict__ kern,
                     const float* __restrict__ bias, float* __restrict__ xp) {
  __shared__ float xs[256][20];
  const int r0 = blockIdx.x * 16;
  const int tid = threadIdx.x;
  for (int idx = tid; idx < 16 * 256; idx += 256) {
    int rr = idx >> 8;
    int k = idx & 255;
    xs[k][rr] = x[(size_t)(r0 + rr) * 256 + k];
  }
  __syncthreads();
  float acc[16][3];
#pragma unroll
  for (int rr = 0; rr < 16; ++rr) {
    acc[rr][0] = bias[tid];
    acc[rr][1] = bias[256 + tid];
    acc[rr][2] = bias[512 + tid];
  }
  for (int k = 0; k < 256; ++k) {
    float k0 = kern[k * 768 + tid];
    float k1 = kern[k * 768 + 256 + tid];
    float k2 = kern[k * 768 + 512 + tid];
#pragma unroll
    for (int rr = 0; rr < 16; ++rr) {
      float xv = xs[k][rr];
      acc[rr][0] = fmaf(xv, k0, acc[rr][0]);
      acc[rr][1] = fmaf(xv, k1, acc[rr][1]);
      acc[rr][2] = fmaf(xv, k2, acc[rr][2]);
    }
  }
  for (int rr = 0; rr < 16; ++rr) {
    xp[(size_t)(r0 + rr) * 768 + tid] = acc[rr][0];
    xp[(size_t)(r0 + rr) * 768 + 256 + tid] = acc[rr][1];
    xp[(size_t)(r0 + rr) * 768 + 512 + tid] = acc[rr][2];
  }
}

// ---------------- main persistent kernel ----------------

__global__ void __launch_bounds__(NT, 2) gru_main(
    const float* __restrict__ att,            // (64,128,256) fp32
    const float* __restrict__ aab,            // after_att_bias (512) fp32
    const unsigned short* __restrict__ kbf,   // kernel bf16 (256x768)
    const unsigned short* __restrict__ rkbf,  // recurrent_kernel bf16 (256x768)
    const unsigned short* __restrict__ aabf,  // after_att_kernel bf16 (256x512)
    const float* __restrict__ xp,             // (4096x768) fp32
    const unsigned int* __restrict__ w1g,     // (53248 x 256) fp8 as u32
    const unsigned int* __restrict__ embg,    // (256 x 53248) fp8 as u32
    unsigned int* __restrict__ s8,            // (64 x 256) fp8 as u32 (64x64)
    unsigned short* __restrict__ pfb,         // [row 64][g 256][col 256] bf16
    float* __restrict__ psum,                 // [row 64][g 256] fp32
    ull_t* __restrict__ bar,
    float* __restrict__ y)                    // d_out (64,64,256) fp32
{
  extern __shared__ char smem[];
  char* w1p  = smem + OFF_W1;
  char* embp = smem + OFF_EMB;
  char* Pp   = smem + OFF_P;
  char* sAp  = smem + OFF_SA;
  float* red4  = (float*)(smem + OFF_SA);            // 16384B (aliases sA)
  float* fbL   = (float*)(smem + OFF_TR);
  float* rhL   = (float*)(smem + OFF_TR + 1024);
  float* cL    = (float*)(smem + OFF_TR + 2048);
  float* s1L   = (float*)(smem + OFF_TR + 3072);
  float* s2L   = (float*)(smem + OFF_TR + 4096);
  float* eL    = (float*)(smem + OFF_TR + 5120);     // 512B
  float* zredL = (float*)(smem + OFF_TR + 5632);     // 1024B
  float* hL    = (float*)(smem + OFF_HL);
  float* zpartL= (float*)(smem + OFF_ZP);            // 64 rows x 2 halves

  const int blk = blockIdx.x;
  const int tid = threadIdx.x;
  const int b = blk;           // batch index when blk < 64
  const int vbase = blk * NV;

  const int w = tid >> 6;      // 0..7
  const int lane = tid & 63;
  const int w2 = w & 3;        // MFMA row-group (batch rows 16*w2..16*w2+15)
  const int half = w >> 2;     // vocab/dt half
  const int lq = lane >> 4;
  const int li = lane & 15;
  // GEMV 4-out-per-lane map: outs [ol, ol+4), K-group kg (8 groups x 32 k)
  const int ol = (tid & 63) * 4;
  const int kg = tid >> 6;

  // ---- prologue: weights -> LDS (once)
  {
    unsigned int* dst = (unsigned int*)w1p;
    for (int i = tid; i < NV * 64; i += NT) {
      int r = i >> 6, c = i & 63;
      dst[r * 66 + c] = w1g[(size_t)(vbase + r) * 64 + c];
    }
    unsigned int* ed = (unsigned int*)embp;
    for (int i = tid; i < 256 * 52; i += NT) {
      int r = i / 52, c = i - r * 52;
      ed[r * 58 + c] = embg[(size_t)r * 13312 + blk * 52 + c];
    }
    for (int i = tid; i < 256 * 6; i += NT) {  // zero emb K-pad cols
      int r = i / 6, c = i - r * 6;
      ed[r * 58 + 52 + c] = 0u;
    }
    unsigned int* Pd = (unsigned int*)Pp;
    for (int i = tid; i < 64 * 6; i += NT) {   // zero P K-pad cols
      int r = i / 6, c = i - r * 6;
      Pd[r * 58 + 52 + c] = 0u;
    }
  }

  auto attention = [&]() {
    // e logits: 128 rows x 4 threads/row (64-dim partials, shfl combine)
    {
      const int r = tid >> 2, q = tid & 3;
      const float* ar = att + (size_t)(b * TAA + r) * DD + q * 64;
      const float* hp = hL + q * 64;
      float l0 = 0.f, l1 = 0.f;
#pragma unroll
      for (int dd = 0; dd < 64; dd += 8) {
        float4 a0 = *reinterpret_cast<const float4*>(ar + dd);
        float4 a1 = *reinterpret_cast<const float4*>(ar + dd + 4);
        l0 += a0.x * hp[dd] + a0.y * hp[dd + 1] + a0.z * hp[dd + 2] + a0.w * hp[dd + 3];
        l1 += a1.x * hp[dd + 4] + a1.y * hp[dd + 5] + a1.z * hp[dd + 6] + a1.w * hp[dd + 7];
      }
      float s = l0 + l1;
      s += __shfl_xor(s, 1);
      s += __shfl_xor(s, 2);
      if (q == 0) eL[r] = s;
    }
    __syncthreads();
    if (tid < 64) {
      float l0 = eL[tid], l1 = eL[tid + 64];
      float m = fmaxf(l0, l1);
#pragma unroll
      for (int off = 32; off > 0; off >>= 1) m = fmaxf(m, __shfl_xor(m, off));
      float e0 = __expf(l0 - m), e1 = __expf(l1 - m);
      float s = e0 + e1;
#pragma unroll
      for (int off = 32; off > 0; off >>= 1) s += __shfl_xor(s, off);
      float inv = 1.0f / s;
      eL[tid] = e0 * inv;
      eL[tid + 64] = e1 * inv;
    }
    __syncthreads();
    // c = e @ att : 256 outs x 2 threads/out (64-ta partials)
    {
      const int d = tid & 255, g = tid >> 8;
      const float* ab = att + (size_t)b * TAA * DD + d;
      float c0 = 0.f, c1 = 0.f;
#pragma unroll 4
      for (int ta = g * 64; ta < g * 64 + 64; ta += 2) {
        c0 += eL[ta] * ab[(size_t)ta * DD];
        c1 += eL[ta + 1] * ab[(size_t)(ta + 1) * DD];
      }
      red4[tid] = c0 + c1;
    }
    __syncthreads();
    if (tid < 256) cL[tid] = red4[tid] + red4[tid + 256];
    __syncthreads();
    // s1: 4 outs/lane, 8-way K-split, ushort4 loads (coalesced 8B/lane)
    {
      float a0 = kg ? 0.f : aab[ol], a1 = kg ? 0.f : aab[ol + 1];
      float a2 = kg ? 0.f : aab[ol + 2], a3 = kg ? 0.f : aab[ol + 3];
#pragma unroll 4
      for (int k = kg * 32; k < kg * 32 + 32; ++k) {
        float c = cL[k];
        ushort4 w4 = *reinterpret_cast<const ushort4*>(aabf + k * 512 + ol);
        a0 += c * bf2f(w4.x); a1 += c * bf2f(w4.y);
        a2 += c * bf2f(w4.z); a3 += c * bf2f(w4.w);
      }
      *reinterpret_cast<float4*>(red4 + kg * 256 + ol) = make_float4(a0, a1, a2, a3);
    }
    __syncthreads();
    if (tid < 256) {
      float s = 0.f;
#pragma unroll
      for (int j = 0; j < 8; ++j) s += red4[tid + j * 256];
      s1L[tid] = tanhf(s);
    }
    __syncthreads();
    // s2: same pattern
    {
      float a0 = kg ? 0.f : aab[256 + ol], a1 = kg ? 0.f : aab[256 + ol + 1];
      float a2 = kg ? 0.f : aab[256 + ol + 2], a3 = kg ? 0.f : aab[256 + ol + 3];
#pragma unroll 4
      for (int k = kg * 32; k < kg * 32 + 32; ++k) {
        float c = s1L[k];
        ushort4 w4 = *reinterpret_cast<const ushort4*>(aabf + k * 512 + 256 + ol);
        a0 += c * bf2f(w4.x); a1 += c * bf2f(w4.y);
        a2 += c * bf2f(w4.z); a3 += c * bf2f(w4.w);
      }
      *reinterpret_cast<float4*>(red4 + kg * 256 + ol) = make_float4(a0, a1, a2, a3);
    }
    __syncthreads();
    if (tid < 256) {
      float s = 0.f;
#pragma unroll
      for (int j = 0; j < 8; ++j) s += red4[tid + j * 256];
      s2L[tid] = tanhf(s);
    }
    __syncthreads();
    if (tid < 64) {
      unsigned int pk = pk4_fp8(s2L[4 * tid], s2L[4 * tid + 1],
                                s2L[4 * tid + 2], s2L[4 * tid + 3]);
      st_u32(s8 + b * 64 + tid, pk);
    }
  };

  auto ca_step = [&](int t) {
    // fb partial reduction: 8 waves x 32 g each; float4 partial stores
    {
      const int g8 = tid >> 6;
      const int dq = tid & 63;
      float a0 = 0, a1 = 0, a2 = 0, a3 = 0;
      const ull_t* base = (const ull_t*)pfb + (size_t)b * (256 * 64) + dq;
      for (int g = g8; g < NBLK; g += 8) {
        ull_t u = ld_u64(base + g * 64);
        a0 += __uint_as_float((unsigned)(u << 16));
        a1 += __uint_as_float((unsigned)u & 0xffff0000u);
        a2 += __uint_as_float(((unsigned)(u >> 16)) & 0xffff0000u);
        a3 += __uint_as_float(((unsigned)(u >> 32)) & 0xffff0000u);
      }
      *reinterpret_cast<float4*>(red4 + g8 * 256 + dq * 4) =
          make_float4(a0, a1, a2, a3);
      if (tid < 256) zredL[tid] = ld_f(psum + b * 256 + tid);
    }
    __syncthreads();
    if (tid < 64) {
      float z2 = zredL[tid] + zredL[tid + 64] + zredL[tid + 128] + zredL[tid + 192];
#pragma unroll
      for (int off = 32; off > 0; off >>= 1) z2 += __shfl_xor(z2, off);
      if (tid == 0) zredL[0] = z2;
    }
    __syncthreads();
    if (tid < 256) {
      float invZ = 1.0f / zredL[0];
      float s = 0.f;
#pragma unroll
      for (int j = 0; j < 8; ++j) s += red4[tid + j * 256];
      fbL[tid] = s * invZ;
    }
    __syncthreads();
    const float* xprow = xp + (size_t)(b * 64 + t) * 768;
    // z,r gates: 4 outs/lane, 8-way K-split, ushort4 loads
    {
      float z0 = kg ? 0.f : xprow[ol],     z1 = kg ? 0.f : xprow[ol + 1];
      float z2 = kg ? 0.f : xprow[ol + 2], z3 = kg ? 0.f : xprow[ol + 3];
      float r0 = kg ? 0.f : xprow[256 + ol],     r1 = kg ? 0.f : xprow[256 + ol + 1];
      float r2 = kg ? 0.f : xprow[256 + ol + 2], r3 = kg ? 0.f : xprow[256 + ol + 3];
#pragma unroll 4
      for (int k = kg * 32; k < kg * 32 + 32; ++k) {
        float fb = fbL[k], h = hL[k];
        ushort4 kz = *reinterpret_cast<const ushort4*>(kbf + k * 768 + ol);
        ushort4 kr = *reinterpret_cast<const ushort4*>(kbf + k * 768 + 256 + ol);
        ushort4 uz = *reinterpret_cast<const ushort4*>(rkbf + k * 768 + ol);
        ushort4 ur = *reinterpret_cast<const ushort4*>(rkbf + k * 768 + 256 + ol);
        z0 += fb * bf2f(kz.x) + h * bf2f(uz.x);
        z1 += fb * bf2f(kz.y) + h * bf2f(uz.y);
        z2 += fb * bf2f(kz.z) + h * bf2f(uz.z);
        z3 += fb * bf2f(kz.w) + h * bf2f(uz.w);
        r0 += fb * bf2f(kr.x) + h * bf2f(ur.x);
        r1 += fb * bf2f(kr.y) + h * bf2f(ur.y);
        r2 += fb * bf2f(kr.z) + h * bf2f(ur.z);
        r3 += fb * bf2f(kr.w) + h * bf2f(ur.w);
      }
      *reinterpret_cast<float4*>(red4 + kg * 256 + ol) = make_float4(z0, z1, z2, z3);
      *reinterpret_cast<float4*>(red4 + 2048 + kg * 256 + ol) = make_float4(r0, r1, r2, r3);
    }
    __syncthreads();
    float zf = 0.f;
    if (tid < 256) {
      float rf = 0.f;
#pragma unroll
      for (int j = 0; j < 8; ++j) {
        zf += red4[tid + j * 256];
        rf += red4[2048 + tid + j * 256];
      }
      rhL[tid] = hsig(rf) * hL[tid];
    }
    __syncthreads();
    // candidate: 4 outs/lane, 8-way K-split
    {
      float h0 = kg ? 0.f : xprow[512 + ol],     h1 = kg ? 0.f : xprow[512 + ol + 1];
      float h2 = kg ? 0.f : xprow[512 + ol + 2], h3 = kg ? 0.f : xprow[512 + ol + 3];
#pragma unroll 4
      for (int k = kg * 32; k < kg * 32 + 32; ++k) {
        float fb = fbL[k], rh = rhL[k];
        ushort4 kh = *reinterpret_cast<const ushort4*>(kbf + k * 768 + 512 + ol);
        ushort4 uh = *reinterpret_cast<const ushort4*>(rkbf + k * 768 + 512 + ol);
        h0 += fb * bf2f(kh.x) + rh * bf2f(uh.x);
        h1 += fb * bf2f(kh.y) + rh * bf2f(uh.y);
        h2 += fb * bf2f(kh.z) + rh * bf2f(uh.z);
        h3 += fb * bf2f(kh.w) + rh * bf2f(uh.w);
      }
      *reinterpret_cast<float4*>(red4 + kg * 256 + ol) = make_float4(h0, h1, h2, h3);
    }
    __syncthreads();
    if (tid < 256) {
      float hp = 0.f;
#pragma unroll
      for (int j = 0; j < 8; ++j) hp += red4[tid + j * 256];
      float hh = tanhf(hp);
      float z = hsig(zf);
      float hn = z * hL[tid] + (1.0f - z) * hh;
      y[(size_t)(b * 64 + t) * 256 + tid] = hn;
      hL[tid] = hn;   // own element: no cross-thread read between write and here
    }
    __syncthreads();
  };

  auto b_phase = [&]() {
    // cooperative sA load: s8 (64x64 u32) -> sA LDS (stride 66 dwords)
    {
      unsigned int* sd = (unsigned int*)sAp;
      for (int i = tid; i < 4096; i += NT) {
        int r = i >> 6, c = i & 63;
        sd[r * 66 + c] = ld_u32(s8 + i);
      }
    }
    __syncthreads();
    // A-frags (s), both halves use row-group w2
    long afr[8];
#pragma unroll
    for (int kk = 0; kk < 8; ++kk)
      afr[kk] = *reinterpret_cast<const long*>(sAp + (16 * w2 + li) * 264 + kk * 32 + lq * 8);
    float sacc[4] = {0.f, 0.f, 0.f, 0.f};
    // logits + exp + P(fp8): vocab tiles split across halves (7 / 6)
    const int vt0 = half ? 7 : 0;
    const int vt1 = half ? 13 : 7;
    for (int vt = vt0; vt < vt1; ++vt) {
      floatx4 lacc = (floatx4){0.f, 0.f, 0.f, 0.f};
#pragma unroll
      for (int kk = 0; kk < 8; ++kk) {
        long bfr = *reinterpret_cast<const long*>(w1p + (vt * 16 + li) * 264 + kk * 32 + lq * 8);
        lacc = __builtin_amdgcn_mfma_f32_16x16x32_fp8_fp8(afr[kk], bfr, lacc, 0, 0, 0);
      }
      const int v = vbase + vt * 16 + li;
      const bool ok = (v < VV);
#pragma unroll
      for (int q = 0; q < 4; ++q) {
        float p = ok ? __expf(lacc[q]) : 0.0f;
        sacc[q] += p;
        unsigned int pb = __builtin_amdgcn_cvt_pk_fp8_f32(p, 0.f, 0u, false);
        Pp[(16 * w2 + lq * 4 + q) * 232 + vt * 16 + li] = (char)(pb & 0xff);
      }
    }
    // partial Z per half -> LDS; combined after barrier
#pragma unroll
    for (int q = 0; q < 4; ++q) {
      float s = sacc[q];
      s += __shfl_xor(s, 1);
      s += __shfl_xor(s, 2);
      s += __shfl_xor(s, 4);
      s += __shfl_xor(s, 8);
      if (li == 0) zpartL[(16 * w2 + lq * 4 + q) * 2 + half] = s;
    }
    __syncthreads();   // P complete (cross-half) + zpart complete
    if (tid < 64) st_f(psum + tid * 256 + blk, zpartL[2 * tid] + zpartL[2 * tid + 1]);
    // fb partial: P(fp8) @ emb(fp8), K = 224; dt tiles split across halves
    long pfr[7];
#pragma unroll
    for (int kk = 0; kk < 7; ++kk)
      pfr[kk] = *reinterpret_cast<const long*>(Pp + (16 * w2 + li) * 232 + kk * 32 + lq * 8);
    const int dt0 = half * 8;
#pragma unroll 4
    for (int dt = dt0; dt < dt0 + 8; ++dt) {
      floatx4 f = (floatx4){0.f, 0.f, 0.f, 0.f};
#pragma unroll
      for (int kk = 0; kk < 7; ++kk) {
        long efr = *reinterpret_cast<const long*>(embp + (dt * 16 + li) * 232 + kk * 32 + lq * 8);
        f = __builtin_amdgcn_mfma_f32_16x16x32_fp8_fp8(pfr[kk], efr, f, 0, 0, 0);
      }
#pragma unroll
      for (int q = 0; q < 4; ++q) {
        int row = 16 * w2 + lq * 4 + q;
        st_u16(pfb + ((size_t)(row * 256 + blk)) * 256 + dt * 16 + li, f2bf(f[q]));
      }
    }
  };

  // ---- t = 0 pre-phase
  __syncthreads();
  if (blk < BB) {
    if (tid < 256) hL[tid] = 0.0f;
    __syncthreads();
    attention();
  }
  gbar(bar, 1);
  for (int t = 0; t < TT; ++t) {
    b_phase();
    gbar(bar, 2 + 2 * t);
    if (blk < BB) {
      ca_step(t);
      attention();
    }
    gbar(bar, 3 + 2 * t);
  }
}

// ---------------- host ----------------

extern "C" void kernel_launch(void* const* d_in, const int* in_sizes, int n_in,
                              void* d_out, int out_size, void* d_ws, size_t ws_size,
                              hipStream_t stream) {
  const float* x    = (const float*)d_in[0];
  const float* att  = (const float*)d_in[1];
  const float* kern = (const float*)d_in[2];
  const float* rk   = (const float*)d_in[3];
  const float* bias = (const float*)d_in[4];
  const float* aak  = (const float*)d_in[5];
  const float* aab  = (const float*)d_in[6];
  const float* w1   = (const float*)d_in[7];
  const float* emb  = (const float*)d_in[8];
  float* y = (float*)d_out;

  char* ws = (char*)d_ws;
  size_t o = 0;
  auto alloc = [&](size_t bytes) {
    char* p = ws + o;
    o += (bytes + 255) & ~(size_t)255;
    return p;
  };
  ull_t* bar = (ull_t*)alloc(2048);
  unsigned int* w1g  = (unsigned int*)alloc((size_t)W1ROWS * 256);       // fp8
  unsigned int* embg = (unsigned int*)alloc((size_t)256 * EMBCOLS);      // fp8
  unsigned short* kbf  = (unsigned short*)alloc((size_t)196608 * 2);
  unsigned short* rkbf = (unsigned short*)alloc((size_t)196608 * 2);
  unsigned short* aabf = (unsigned short*)alloc((size_t)131072 * 2);
  float* xp  = (float*)alloc((size_t)4096 * 768 * 4);
  unsigned int* s8 = (unsigned int*)alloc((size_t)64 * 64 * 4);
  unsigned short* pfb = (unsigned short*)alloc((size_t)64 * 256 * 256 * 2);
  float* psum = (float*)alloc((size_t)64 * 256 * 4);
  (void)ws_size; (void)in_sizes; (void)n_in; (void)out_size;

  static bool attr_done = false;
  if (!attr_done) {
    hipFuncSetAttribute((const void*)gru_main,
                        hipFuncAttributeMaxDynamicSharedMemorySize, SMEM_BYTES);
    attr_done = true;
  }

  hipMemsetAsync(bar, 0, 2048, stream);
  hipLaunchKernelGGL(k_f2bf, dim3(768), dim3(256), 0, stream, kern, kbf, 196608);
  hipLaunchKernelGGL(k_f2bf, dim3(768), dim3(256), 0, stream, rk, rkbf, 196608);
  hipLaunchKernelGGL(k_f2bf, dim3(512), dim3(256), 0, stream, aak, aabf, 131072);
  hipLaunchKernelGGL(k_tw1, dim3(1664, 8), dim3(32, 8), 0, stream, w1, w1g);
  hipLaunchKernelGGL(k_temb, dim3(1664, 8), dim3(32, 8), 0, stream, emb, embg);
  hipLaunchKernelGGL(k_xp, dim3(256), dim3(256), 0, stream, x, kern, bias, xp);
  hipLaunchKernelGGL(gru_main, dim3(NBLK), dim3(NT), SMEM_BYTES, stream,
                     att, aab, kbf, rkbf, aabf, xp, w1g, embg, s8, pfb, psum, bar, y);
}

// Round 7
// 2873.508 us; speedup vs baseline: 3.5359x; 1.3046x over previous
//
#include <hip/hip_runtime.h>

#define BB 64
#define TT 64
#define DD 256
#define TAA 128
#define UU 256
#define VV 50257
#define NBLK 256
#define NV 208           // vocab span per block (13 x 16)
#define NVK 224          // padded K for fb GEMM (7 x 32)
#define W1ROWS 53248     // NBLK*NV, zero-padded rows >= VV
#define EMBCOLS 53248
#define NT 512           // threads per block (8 waves): 2 waves/SIMD (R1-verified)
// LDS layout (bytes) — identical to the verified R1 kernel
#define OFF_W1   0                   // 208 rows x 264B  (stride 66 dwords)
#define OFF_EMB  54912               // 256 rows x 232B  (stride 58 dwords)
#define OFF_P    114304              // 64 rows x 232B
#define OFF_SA   129152              // 64 rows x 264B   (ca transients alias here)
#define OFF_HL   146048              // 256 floats
#define OFF_ZP   147072              // 64 rows x 2 halves partial-Z (512B)
#define SMEM_BYTES 147712

typedef __attribute__((ext_vector_type(4))) float floatx4;
typedef unsigned long long ull_t;

__device__ __forceinline__ float bf2f(unsigned short u) {
  union { unsigned int i; float f; } c; c.i = ((unsigned int)u) << 16; return c.f;
}
__device__ __forceinline__ unsigned short f2bf(float f) {
  union { float f; unsigned int i; } c; c.f = f;
  return (unsigned short)((c.i + 0x7fffu + ((c.i >> 16) & 1u)) >> 16);
}
__device__ __forceinline__ float hsig(float x) {
  return fminf(1.0f, fmaxf(0.0f, 0.2f * x + 0.5f));
}
__device__ __forceinline__ unsigned int pk4_fp8(float a, float b, float c, float d) {
  unsigned int r = 0;
  r = __builtin_amdgcn_cvt_pk_fp8_f32(a, b, r, false);
  r = __builtin_amdgcn_cvt_pk_fp8_f32(c, d, r, true);
  return r;
}

// ---- coherent (cross-XCD) per-access ops; no cache-walk fences
__device__ __forceinline__ void st_f(float* p, float v) {
  __hip_atomic_store(p, v, __ATOMIC_RELAXED, __HIP_MEMORY_SCOPE_AGENT);
}
__device__ __forceinline__ float ld_f(const float* p) {
  return __hip_atomic_load(p, __ATOMIC_RELAXED, __HIP_MEMORY_SCOPE_AGENT);
}
__device__ __forceinline__ void st_u16(unsigned short* p, unsigned short v) {
  __hip_atomic_store(p, v, __ATOMIC_RELAXED, __HIP_MEMORY_SCOPE_AGENT);
}
__device__ __forceinline__ void st_u32(unsigned int* p, unsigned int v) {
  __hip_atomic_store(p, v, __ATOMIC_RELAXED, __HIP_MEMORY_SCOPE_AGENT);
}
__device__ __forceinline__ unsigned int ld_u32(const unsigned int* p) {
  return __hip_atomic_load(p, __ATOMIC_RELAXED, __HIP_MEMORY_SCOPE_AGENT);
}
__device__ __forceinline__ ull_t ld_u64(const ull_t* p) {
  return __hip_atomic_load(p, __ATOMIC_RELAXED, __HIP_MEMORY_SCOPE_AGENT);
}

// hierarchical barrier: 8 arrival lines (128B apart) + master line
__device__ __forceinline__ void gbar(ull_t* bar, int phase) {
  asm volatile("s_waitcnt vmcnt(0)" ::: "memory");
  __syncthreads();
  if (threadIdx.x == 0) {
    ull_t* myc = (ull_t*)((char*)bar + 128 * (1 + (blockIdx.x & 7)));
    ull_t t1 = __hip_atomic_fetch_add(myc, 1ull, __ATOMIC_RELAXED,
                                      __HIP_MEMORY_SCOPE_AGENT) + 1ull;
    if (t1 == (ull_t)(32 * phase)) {
      __hip_atomic_fetch_add(bar, 1ull, __ATOMIC_RELAXED, __HIP_MEMORY_SCOPE_AGENT);
    }
    while (__hip_atomic_load(bar, __ATOMIC_RELAXED, __HIP_MEMORY_SCOPE_AGENT) <
           (ull_t)(8 * phase))
      __builtin_amdgcn_s_sleep(4);
  }
  __syncthreads();
}

// ---------------- prep kernels ----------------

__global__ void k_f2bf(const float* __restrict__ in, unsigned short* __restrict__ out, int n) {
  int i = blockIdx.x * 256 + threadIdx.x;
  int stride = gridDim.x * 256;
  for (; i < n; i += stride) out[i] = f2bf(in[i]);
}

// W_o1 (256 x 50257) fp32 -> w1g (53248 x 256) fp8, zero-padded rows
__global__ void k_tw1(const float* __restrict__ w, unsigned int* __restrict__ o) {
  __shared__ float tile[32][33];  // [k_local][v_local]
  const int bx = blockIdx.x, by = blockIdx.y;
  const int tx = threadIdx.x, ty = threadIdx.y;
#pragma unroll
  for (int i = 0; i < 4; ++i) {
    int k = by * 32 + ty + i * 8;
    int v = bx * 32 + tx;
    tile[ty + i * 8][tx] = (v < VV) ? w[(size_t)k * VV + v] : 0.0f;
  }
  __syncthreads();
  const int t = ty * 32 + tx;      // 0..255
  const int vl = t >> 3;           // 0..31
  const int cg = t & 7;            // 0..7 (4 k each)
  unsigned int pk = pk4_fp8(tile[cg * 4 + 0][vl], tile[cg * 4 + 1][vl],
                            tile[cg * 4 + 2][vl], tile[cg * 4 + 3][vl]);
  o[(size_t)(bx * 32 + vl) * 64 + by * 8 + cg] = pk;
}

// embedding (50257 x 256) fp32 -> embg (256 x 53248) fp8, zero-padded cols
__global__ void k_temb(const float* __restrict__ e, unsigned int* __restrict__ o) {
  __shared__ float tile[32][33];  // [v_local][d_local]
  const int bx = blockIdx.x, by = blockIdx.y;
  const int tx = threadIdx.x, ty = threadIdx.y;
#pragma unroll
  for (int i = 0; i < 4; ++i) {
    int v = bx * 32 + ty + i * 8;
    int d = by * 32 + tx;
    tile[ty + i * 8][tx] = (v < VV) ? e[(size_t)v * 256 + d] : 0.0f;
  }
  __syncthreads();
  const int t = ty * 32 + tx;
  const int dl = t >> 3;           // 0..31
  const int vg = t & 7;            // 0..7 (4 v each)
  unsigned int pk = pk4_fp8(tile[vg * 4 + 0][dl], tile[vg * 4 + 1][dl],
                            tile[vg * 4 + 2][dl], tile[vg * 4 + 3][dl]);
  o[(size_t)(by * 32 + dl) * 13312 + bx * 8 + vg] = pk;
}

// xp = x(4096x256) @ kernel(256x768) + bias, fp32
__global__ void k_xp(const float* __restrict__ x, const float* __restrict__ kern,
                     const float* __restrict__ bias, float* __restrict__ xp) {
  __shared__ float xs[256][20];
  const int r0 = blockIdx.x * 16;
  const int tid = threadIdx.x;
  for (int idx = tid; idx < 16 * 256; idx += 256) {
    int rr = idx >> 8;
    int k = idx & 255;
    xs[k][rr] = x[(size_t)(r0 + rr) * 256 + k];
  }
  __syncthreads();
  float acc[16][3];
#pragma unroll
  for (int rr = 0; rr < 16; ++rr) {
    acc[rr][0] = bias[tid];
    acc[rr][1] = bias[256 + tid];
    acc[rr][2] = bias[512 + tid];
  }
  for (int k = 0; k < 256; ++k) {
    float k0 = kern[k * 768 + tid];
    float k1 = kern[k * 768 + 256 + tid];
    float k2 = kern[k * 768 + 512 + tid];
#pragma unroll
    for (int rr = 0; rr < 16; ++rr) {
      float xv = xs[k][rr];
      acc[rr][0] = fmaf(xv, k0, acc[rr][0]);
      acc[rr][1] = fmaf(xv, k1, acc[rr][1]);
      acc[rr][2] = fmaf(xv, k2, acc[rr][2]);
    }
  }
  for (int rr = 0; rr < 16; ++rr) {
    xp[(size_t)(r0 + rr) * 768 + tid] = acc[rr][0];
    xp[(size_t)(r0 + rr) * 768 + 256 + tid] = acc[rr][1];
    xp[(size_t)(r0 + rr) * 768 + 512 + tid] = acc[rr][2];
  }
}

// ---------------- main persistent kernel ----------------

__global__ void __launch_bounds__(NT, 2) gru_main(
    const float* __restrict__ att,            // (64,128,256) fp32
    const float* __restrict__ aab,            // after_att_bias (512) fp32
    const unsigned short* __restrict__ kbf,   // kernel bf16 (256x768)
    const unsigned short* __restrict__ rkbf,  // recurrent_kernel bf16 (256x768)
    const unsigned short* __restrict__ aabf,  // after_att_kernel bf16 (256x512)
    const float* __restrict__ xp,             // (4096x768) fp32
    const unsigned int* __restrict__ w1g,     // (53248 x 256) fp8 as u32
    const unsigned int* __restrict__ embg,    // (256 x 53248) fp8 as u32
    unsigned int* __restrict__ s8,            // (64 x 256) fp8 as u32 (64x64)
    unsigned short* __restrict__ pfb,         // [row 64][g 256][col 256] bf16
    float* __restrict__ psum,                 // [row 64][g 256] fp32
    float* __restrict__ fbp4,                 // [batch 64][quarter 4][256] fp32
    ull_t* __restrict__ hflag,                // [batch 64] x 128B lines
    ull_t* __restrict__ bar,
    float* __restrict__ y)                    // d_out (64,64,256) fp32
{
  extern __shared__ char smem[];
  char* w1p  = smem + OFF_W1;
  char* embp = smem + OFF_EMB;
  char* Pp   = smem + OFF_P;
  char* sAp  = smem + OFF_SA;
  float* red4  = (float*)(smem + OFF_SA);           // 8192B (8x256 partials)
  float* fbL   = (float*)(smem + OFF_SA + 8192);
  float* rhL   = (float*)(smem + OFF_SA + 9216);
  float* cL    = (float*)(smem + OFF_SA + 10240);
  float* s1L   = (float*)(smem + OFF_SA + 11264);
  float* s2L   = (float*)(smem + OFF_SA + 12288);
  float* eL    = (float*)(smem + OFF_SA + 13312);   // 512B
  float* zredL = (float*)(smem + OFF_SA + 13824);   // 1024B
  float* hL    = (float*)(smem + OFF_HL);
  float* zpartL= (float*)(smem + OFF_ZP);           // 64 rows x 2 halves

  const int blk = blockIdx.x;
  const int tid = threadIdx.x;
  const int b = blk;           // batch index when blk < 64
  const int vbase = blk * NV;

  const int w = tid >> 6;      // 0..7
  const int lane = tid & 63;
  const int w2 = w & 3;        // MFMA row-group (batch rows 16*w2..16*w2+15)
  const int half = w >> 2;     // vocab/dt half
  const int lq = lane >> 4;
  const int li = lane & 15;
  const int hb = blk & 63;     // helper: batch served
  const int hq = blk >> 6;     // helper: g-quarter served

  // ---- prologue: weights -> LDS (once)
  {
    unsigned int* dst = (unsigned int*)w1p;
    for (int i = tid; i < NV * 64; i += NT) {
      int r = i >> 6, c = i & 63;
      dst[r * 66 + c] = w1g[(size_t)(vbase + r) * 64 + c];
    }
    unsigned int* ed = (unsigned int*)embp;
    for (int i = tid; i < 256 * 52; i += NT) {
      int r = i / 52, c = i - r * 52;
      ed[r * 58 + c] = embg[(size_t)r * 13312 + blk * 52 + c];
    }
    for (int i = tid; i < 256 * 6; i += NT) {  // zero emb K-pad cols
      int r = i / 6, c = i - r * 6;
      ed[r * 58 + 52 + c] = 0u;
    }
    unsigned int* Pd = (unsigned int*)Pp;
    for (int i = tid; i < 64 * 6; i += NT) {   // zero P K-pad cols
      int r = i / 6, c = i - r * 6;
      Pd[r * 58 + 52 + c] = 0u;
    }
  }

  auto attention = [&]() {
    // e logits: 128 rows x 4 threads/row (64-dim partials, shfl combine)
    {
      const int r = tid >> 2, q = tid & 3;
      const float* ar = att + (size_t)(b * TAA + r) * DD + q * 64;
      const float* hp = hL + q * 64;
      float l0 = 0.f, l1 = 0.f;
#pragma unroll
      for (int dd = 0; dd < 64; dd += 8) {
        float4 a0 = *reinterpret_cast<const float4*>(ar + dd);
        float4 a1 = *reinterpret_cast<const float4*>(ar + dd + 4);
        l0 += a0.x * hp[dd] + a0.y * hp[dd + 1] + a0.z * hp[dd + 2] + a0.w * hp[dd + 3];
        l1 += a1.x * hp[dd + 4] + a1.y * hp[dd + 5] + a1.z * hp[dd + 6] + a1.w * hp[dd + 7];
      }
      float s = l0 + l1;
      s += __shfl_xor(s, 1);
      s += __shfl_xor(s, 2);
      if (q == 0) eL[r] = s;
    }
    __syncthreads();
    if (tid < 64) {
      float l0 = eL[tid], l1 = eL[tid + 64];
      float m = fmaxf(l0, l1);
#pragma unroll
      for (int off = 32; off > 0; off >>= 1) m = fmaxf(m, __shfl_xor(m, off));
      float e0 = __expf(l0 - m), e1 = __expf(l1 - m);
      float s = e0 + e1;
#pragma unroll
      for (int off = 32; off > 0; off >>= 1) s += __shfl_xor(s, off);
      float inv = 1.0f / s;
      eL[tid] = e0 * inv;
      eL[tid + 64] = e1 * inv;
    }
    __syncthreads();
    // c = e @ att : 256 outs x 2 threads/out (64-ta partials)
    {
      const int d = tid & 255, g = tid >> 8;
      const float* ab = att + (size_t)b * TAA * DD + d;
      float c0 = 0.f, c1 = 0.f;
#pragma unroll 4
      for (int ta = g * 64; ta < g * 64 + 64; ta += 2) {
        c0 += eL[ta] * ab[(size_t)ta * DD];
        c1 += eL[ta + 1] * ab[(size_t)(ta + 1) * DD];
      }
      red4[tid] = c0 + c1;
    }
    __syncthreads();
    if (tid < 256) cL[tid] = red4[tid] + red4[tid + 256];
    __syncthreads();
    // s1: 256 outs x 2 threads/out (128-k partials)
    {
      const int out = tid & 255, g = tid >> 8;
      float a0 = g ? 0.f : aab[out], a1 = 0.f;
      for (int k = g * 128; k < g * 128 + 128; k += 2) {
        a0 += cL[k] * bf2f(aabf[k * 512 + out]);
        a1 += cL[k + 1] * bf2f(aabf[(k + 1) * 512 + out]);
      }
      red4[tid] = a0 + a1;
    }
    __syncthreads();
    if (tid < 256) s1L[tid] = tanhf(red4[tid] + red4[tid + 256]);
    __syncthreads();
    // s2
    {
      const int out = tid & 255, g = tid >> 8;
      float a0 = g ? 0.f : aab[256 + out], a1 = 0.f;
      for (int k = g * 128; k < g * 128 + 128; k += 2) {
        a0 += s1L[k] * bf2f(aabf[k * 512 + 256 + out]);
        a1 += s1L[k + 1] * bf2f(aabf[(k + 1) * 512 + 256 + out]);
      }
      red4[tid] = a0 + a1;
    }
    __syncthreads();
    if (tid < 256) s2L[tid] = tanhf(red4[tid] + red4[tid + 256]);
    __syncthreads();
    if (tid < 64) {
      unsigned int pk = pk4_fp8(s2L[4 * tid], s2L[4 * tid + 1],
                                s2L[4 * tid + 2], s2L[4 * tid + 3]);
      st_u32(s8 + b * 64 + tid, pk);
    }
  };

  // ---- distributed fb pre-reduce: EVERY block reduces its 64-g quarter of
  // batch hb into a 256-f32 partial, then bumps hb's flag. The 192 blocks
  // that were idle during the GRU half now carry 3/4 of the gather traffic.
  auto helper_reduce = [&]() {
    {
      const int gl = tid >> 6;     // 0..7
      const int dq = tid & 63;
      float a0 = 0, a1 = 0, a2 = 0, a3 = 0;
      const ull_t* base = (const ull_t*)pfb + (size_t)hb * (256 * 64) + dq;
      const int g0 = hq * 64 + gl;
#pragma unroll
      for (int i = 0; i < 8; ++i) {
        ull_t u = ld_u64(base + (size_t)(g0 + i * 8) * 64);
        a0 += __uint_as_float((unsigned)(u << 16));
        a1 += __uint_as_float((unsigned)u & 0xffff0000u);
        a2 += __uint_as_float(((unsigned)(u >> 16)) & 0xffff0000u);
        a3 += __uint_as_float(((unsigned)(u >> 32)) & 0xffff0000u);
      }
      *reinterpret_cast<float4*>(red4 + gl * 256 + dq * 4) =
          make_float4(a0, a1, a2, a3);
    }
    __syncthreads();
    if (tid < 256) {
      float s = 0.f;
#pragma unroll
      for (int j = 0; j < 8; ++j) s += red4[tid + j * 256];
      st_f(fbp4 + ((size_t)hb * 4 + hq) * 256 + tid, s);
    }
    asm volatile("s_waitcnt vmcnt(0)" ::: "memory");
    __syncthreads();
    if (tid == 0)
      __hip_atomic_fetch_add(hflag + (size_t)hb * 16, 1ull, __ATOMIC_RELAXED,
                             __HIP_MEMORY_SCOPE_AGENT);
  };

  auto ca_step = [&](int t) {
    // Z gather (overlaps with remote helpers finishing their fb quarters)
    if (tid < 256) zredL[tid] = ld_f(psum + b * 256 + tid);
    __syncthreads();
    if (tid < 64) {
      float z2 = zredL[tid] + zredL[tid + 64] + zredL[tid + 128] + zredL[tid + 192];
#pragma unroll
      for (int off = 32; off > 0; off >>= 1) z2 += __shfl_xor(z2, off);
      if (tid == 0) zredL[0] = z2;
    }
    // wait for all 4 fb quarters of this batch (monotonic flag: 4 per step)
    if (tid == 0) {
      while (__hip_atomic_load(hflag + (size_t)b * 16, __ATOMIC_RELAXED,
                               __HIP_MEMORY_SCOPE_AGENT) < (ull_t)(4 * (t + 1)))
        __builtin_amdgcn_s_sleep(2);
    }
    __syncthreads();
    if (tid < 256) {
      float invZ = 1.0f / zredL[0];
      const float* fp = fbp4 + (size_t)b * 1024;
      fbL[tid] = (ld_f(fp + tid) + ld_f(fp + 256 + tid) +
                  ld_f(fp + 512 + tid) + ld_f(fp + 768 + tid)) * invZ;
    }
    __syncthreads();
    const float* xprow = xp + (size_t)(b * 64 + t) * 768;
    float z0 = xprow[tid & 255], z1 = 0.f;   // (tid<512: out = tid&255, g = tid>>8)
    const int out = tid & 255, g = tid >> 8;
    z0 = g ? 0.f : xprow[out];
    float r0 = g ? 0.f : xprow[256 + out], r1 = 0.f;
    for (int k = g * 128; k < g * 128 + 128; k += 2) {
      float fb0 = fbL[k], h0 = hL[k], fb1 = fbL[k + 1], h1 = hL[k + 1];
      const unsigned short* kp0 = kbf + k * 768 + out;
      const unsigned short* up0 = rkbf + k * 768 + out;
      z0 += fb0 * bf2f(kp0[0]) + h0 * bf2f(up0[0]);
      r0 += fb0 * bf2f(kp0[256]) + h0 * bf2f(up0[256]);
      z1 += fb1 * bf2f(kp0[768]) + h1 * bf2f(up0[768]);
      r1 += fb1 * bf2f(kp0[1024]) + h1 * bf2f(up0[1024]);
    }
    red4[tid] = z0 + z1;
    red4[512 + tid] = r0 + r1;
    __syncthreads();
    float zf = 0.f;
    if (tid < 256) {
      zf = red4[tid] + red4[tid + 256];
      float rf = red4[512 + tid] + red4[768 + tid];
      rhL[tid] = hsig(rf) * hL[tid];
    }
    __syncthreads();
    // candidate: 2 threads/out, 128-k partials
    {
      float hp0 = g ? 0.f : xprow[512 + out], hp1 = 0.f;
      for (int k = g * 128; k < g * 128 + 128; k += 2) {
        hp0 += fbL[k] * bf2f(kbf[k * 768 + 512 + out]) +
               rhL[k] * bf2f(rkbf[k * 768 + 512 + out]);
        hp1 += fbL[k + 1] * bf2f(kbf[(k + 1) * 768 + 512 + out]) +
               rhL[k + 1] * bf2f(rkbf[(k + 1) * 768 + 512 + out]);
      }
      red4[1024 + tid] = hp0 + hp1;
    }
    __syncthreads();
    if (tid < 256) {
      float hh = tanhf(red4[1024 + tid] + red4[1280 + tid]);
      float z = hsig(zf);
      float hn = z * hL[tid] + (1.0f - z) * hh;
      y[(size_t)(b * 64 + t) * 256 + tid] = hn;
      hL[tid] = hn;   // own element: no cross-thread read between write and here
    }
    __syncthreads();
  };

  auto b_phase = [&]() {
    // cooperative sA load: s8 (64x64 u32) -> sA LDS (stride 66 dwords)
    {
      unsigned int* sd = (unsigned int*)sAp;
      for (int i = tid; i < 4096; i += NT) {
        int r = i >> 6, c = i & 63;
        sd[r * 66 + c] = ld_u32(s8 + i);
      }
    }
    __syncthreads();
    // A-frags (s), both halves use row-group w2
    long afr[8];
#pragma unroll
    for (int kk = 0; kk < 8; ++kk)
      afr[kk] = *reinterpret_cast<const long*>(sAp + (16 * w2 + li) * 264 + kk * 32 + lq * 8);
    float sacc[4] = {0.f, 0.f, 0.f, 0.f};
    // logits + exp + P(fp8): vocab tiles split across halves (7 / 6)
    const int vt0 = half ? 7 : 0;
    const int vt1 = half ? 13 : 7;
    for (int vt = vt0; vt < vt1; ++vt) {
      floatx4 lacc = (floatx4){0.f, 0.f, 0.f, 0.f};
#pragma unroll
      for (int kk = 0; kk < 8; ++kk) {
        long bfr = *reinterpret_cast<const long*>(w1p + (vt * 16 + li) * 264 + kk * 32 + lq * 8);
        lacc = __builtin_amdgcn_mfma_f32_16x16x32_fp8_fp8(afr[kk], bfr, lacc, 0, 0, 0);
      }
      const int v = vbase + vt * 16 + li;
      const bool ok = (v < VV);
#pragma unroll
      for (int q = 0; q < 4; ++q) {
        float p = ok ? __expf(lacc[q]) : 0.0f;
        sacc[q] += p;
        unsigned int pb = __builtin_amdgcn_cvt_pk_fp8_f32(p, 0.f, 0u, false);
        Pp[(16 * w2 + lq * 4 + q) * 232 + vt * 16 + li] = (char)(pb & 0xff);
      }
    }
    // partial Z per half -> LDS; combined after barrier
#pragma unroll
    for (int q = 0; q < 4; ++q) {
      float s = sacc[q];
      s += __shfl_xor(s, 1);
      s += __shfl_xor(s, 2);
      s += __shfl_xor(s, 4);
      s += __shfl_xor(s, 8);
      if (li == 0) zpartL[(16 * w2 + lq * 4 + q) * 2 + half] = s;
    }
    __syncthreads();   // P complete (cross-half) + zpart complete
    if (tid < 64) st_f(psum + tid * 256 + blk, zpartL[2 * tid] + zpartL[2 * tid + 1]);
    // fb partial: P(fp8) @ emb(fp8), K = 224; dt tiles split across halves
    long pfr[7];
#pragma unroll
    for (int kk = 0; kk < 7; ++kk)
      pfr[kk] = *reinterpret_cast<const long*>(Pp + (16 * w2 + li) * 232 + kk * 32 + lq * 8);
    const int dt0 = half * 8;
#pragma unroll 4
    for (int dt = dt0; dt < dt0 + 8; ++dt) {
      floatx4 f = (floatx4){0.f, 0.f, 0.f, 0.f};
#pragma unroll
      for (int kk = 0; kk < 7; ++kk) {
        long efr = *reinterpret_cast<const long*>(embp + (dt * 16 + li) * 232 + kk * 32 + lq * 8);
        f = __builtin_amdgcn_mfma_f32_16x16x32_fp8_fp8(pfr[kk], efr, f, 0, 0, 0);
      }
#pragma unroll
      for (int q = 0; q < 4; ++q) {
        int row = 16 * w2 + lq * 4 + q;
        st_u16(pfb + ((size_t)(row * 256 + blk)) * 256 + dt * 16 + li, f2bf(f[q]));
      }
    }
  };

  // ---- t = 0 pre-phase
  __syncthreads();
  if (blk < BB) {
    if (tid < 256) hL[tid] = 0.0f;
    __syncthreads();
    attention();
  }
  gbar(bar, 1);
  for (int t = 0; t < TT; ++t) {
    b_phase();
    gbar(bar, 2 + 2 * t);
    helper_reduce();                 // all 256 blocks: 1/4 of one batch's fb
    if (blk < BB) {
      ca_step(t);
      attention();
    }
    gbar(bar, 3 + 2 * t);
  }
}

// ---------------- host ----------------

extern "C" void kernel_launch(void* const* d_in, const int* in_sizes, int n_in,
                              void* d_out, int out_size, void* d_ws, size_t ws_size,
                              hipStream_t stream) {
  const float* x    = (const float*)d_in[0];
  const float* att  = (const float*)d_in[1];
  const float* kern = (const float*)d_in[2];
  const float* rk   = (const float*)d_in[3];
  const float* bias = (const float*)d_in[4];
  const float* aak  = (const float*)d_in[5];
  const float* aab  = (const float*)d_in[6];
  const float* w1   = (const float*)d_in[7];
  const float* emb  = (const float*)d_in[8];
  float* y = (float*)d_out;

  char* ws = (char*)d_ws;
  size_t o = 0;
  auto alloc = [&](size_t bytes) {
    char* p = ws + o;
    o += (bytes + 255) & ~(size_t)255;
    return p;
  };
  ull_t* bar   = (ull_t*)alloc(2048);
  ull_t* hflag = (ull_t*)alloc(8192);                 // 64 x 128B lines (contiguous after bar)
  unsigned int* w1g  = (unsigned int*)alloc((size_t)W1ROWS * 256);       // fp8
  unsigned int* embg = (unsigned int*)alloc((size_t)256 * EMBCOLS);      // fp8
  unsigned short* kbf  = (unsigned short*)alloc((size_t)196608 * 2);
  unsigned short* rkbf = (unsigned short*)alloc((size_t)196608 * 2);
  unsigned short* aabf = (unsigned short*)alloc((size_t)131072 * 2);
  float* xp  = (float*)alloc((size_t)4096 * 768 * 4);
  unsigned int* s8 = (unsigned int*)alloc((size_t)64 * 64 * 4);
  unsigned short* pfb = (unsigned short*)alloc((size_t)64 * 256 * 256 * 2);
  float* psum = (float*)alloc((size_t)64 * 256 * 4);
  float* fbp4 = (float*)alloc((size_t)64 * 4 * 256 * 4);
  (void)ws_size; (void)in_sizes; (void)n_in; (void)out_size;

  static bool attr_done = false;
  if (!attr_done) {
    hipFuncSetAttribute((const void*)gru_main,
                        hipFuncAttributeMaxDynamicSharedMemorySize, SMEM_BYTES);
    attr_done = true;
  }

  hipMemsetAsync(bar, 0, 2048 + 8192, stream);   // bar + hflag
  hipLaunchKernelGGL(k_f2bf, dim3(768), dim3(256), 0, stream, kern, kbf, 196608);
  hipLaunchKernelGGL(k_f2bf, dim3(768), dim3(256), 0, stream, rk, rkbf, 196608);
  hipLaunchKernelGGL(k_f2bf, dim3(512), dim3(256), 0, stream, aak, aabf, 131072);
  hipLaunchKernelGGL(k_tw1, dim3(1664, 8), dim3(32, 8), 0, stream, w1, w1g);
  hipLaunchKernelGGL(k_temb, dim3(1664, 8), dim3(32, 8), 0, stream, emb, embg);
  hipLaunchKernelGGL(k_xp, dim3(256), dim3(256), 0, stream, x, kern, bias, xp);
  hipLaunchKernelGGL(gru_main, dim3(NBLK), dim3(NT), SMEM_BYTES, stream,
                     att, aab, kbf, rkbf, aabf, xp, w1g, embg, s8, pfb, psum,
                     fbp4, hflag, bar, y);
}